// Round 1
// baseline (2213.965 us; speedup 1.0000x reference)
//
#include <hip/hip_runtime.h>
#include <math.h>

#define Bsz 4
#define Cch 256
#define Npt 2048
#define Hh  4
#define NL  4
#define BN_CNT (Bsz * Npt)   // 8192
#define EPSV 1e-5f

// ---------------- xyz embedding: emb[b,c,n] = pos_w[c,:]·xyz[b,n,:] + pos_b[c] ----------------
__global__ void k_xyz_emb(const float* __restrict__ xyz, const float* __restrict__ pw,
                          const float* __restrict__ pb, float* __restrict__ emb) {
    int idx = blockIdx.x * 256 + threadIdx.x;   // B*C*N threads
    int n = idx & (Npt - 1);
    int c = (idx >> 11) & (Cch - 1);
    int b = idx >> 19;
    const float* xz = xyz + (b * Npt + n) * 3;
    emb[idx] = pw[c * 3 + 0] * xz[0] + pw[c * 3 + 1] * xz[1] + pw[c * 3 + 2] * xz[2] + pb[c];
}

// ---------------- elementwise add (float4): o = a + b ----------------
__global__ void k_add(const float* __restrict__ a, const float* __restrict__ b,
                      float* __restrict__ o) {
    int i = blockIdx.x * 256 + threadIdx.x;
    float4 av = ((const float4*)a)[i], bv = ((const float4*)b)[i];
    ((float4*)o)[i] = make_float4(av.x + bv.x, av.y + bv.y, av.z + bv.z, av.w + bv.w);
}

// ---------------- GEMM: Y[b,o,n] = sum_c W[o,c] * X[b,c,n] (+ bias[o]) ----------------
// grid (N/64, 256/64, B), block 256; 64x64 tile, 4x4 micro-tile, K-step 16
__global__ __launch_bounds__(256) void k_gemm(const float* __restrict__ W,
        const float* __restrict__ X, const float* __restrict__ bias, float* __restrict__ Y) {
    __shared__ float Wt[64][17];
    __shared__ float Xt[16][68];
    const int b  = blockIdx.z;
    const int o0 = blockIdx.y * 64;
    const int n0 = blockIdx.x * 64;
    const int tid = threadIdx.x;
    const int tx = tid & 15, ty = tid >> 4;
    const float* Xb = X + b * (Cch * Npt);
    float acc[4][4] = {{0.f}};
    for (int k0 = 0; k0 < Cch; k0 += 16) {
        { int r = tid >> 2, kq = (tid & 3) << 2;
          float4 w4 = *(const float4*)(W + (o0 + r) * Cch + k0 + kq);
          Wt[r][kq] = w4.x; Wt[r][kq + 1] = w4.y; Wt[r][kq + 2] = w4.z; Wt[r][kq + 3] = w4.w; }
        { int r = tid >> 4, nq = (tid & 15) << 2;
          float4 x4 = *(const float4*)(Xb + (k0 + r) * Npt + n0 + nq);
          Xt[r][nq] = x4.x; Xt[r][nq + 1] = x4.y; Xt[r][nq + 2] = x4.z; Xt[r][nq + 3] = x4.w; }
        __syncthreads();
        #pragma unroll
        for (int kk = 0; kk < 16; ++kk) {
            float a0 = Wt[ty * 4 + 0][kk], a1 = Wt[ty * 4 + 1][kk];
            float a2 = Wt[ty * 4 + 2][kk], a3 = Wt[ty * 4 + 3][kk];
            float b0 = Xt[kk][tx * 4 + 0], b1 = Xt[kk][tx * 4 + 1];
            float b2 = Xt[kk][tx * 4 + 2], b3 = Xt[kk][tx * 4 + 3];
            acc[0][0] += a0 * b0; acc[0][1] += a0 * b1; acc[0][2] += a0 * b2; acc[0][3] += a0 * b3;
            acc[1][0] += a1 * b0; acc[1][1] += a1 * b1; acc[1][2] += a1 * b2; acc[1][3] += a1 * b3;
            acc[2][0] += a2 * b0; acc[2][1] += a2 * b1; acc[2][2] += a2 * b2; acc[2][3] += a2 * b3;
            acc[3][0] += a3 * b0; acc[3][1] += a3 * b1; acc[3][2] += a3 * b2; acc[3][3] += a3 * b3;
        }
        __syncthreads();
    }
    #pragma unroll
    for (int i = 0; i < 4; ++i) {
        int o = o0 + ty * 4 + i;
        float bi = bias ? bias[o] : 0.f;
        float* yp = Y + b * (Cch * Npt) + o * Npt + n0 + tx * 4;
        yp[0] = acc[i][0] + bi; yp[1] = acc[i][1] + bi;
        yp[2] = acc[i][2] + bi; yp[3] = acc[i][3] + bi;
    }
}

// x_q[b,hd,i,d] = q[b, (i%4)*64+d, hd*512 + i/4]   (the quirky reshape)
// x_k[b,hd,d,j] = q[b, hd*64+d, j]

// ---------------- attention pass A: row max + row sumexp of E = Q·K ----------------
// grid (32 i-tiles, H, B), block 256
__global__ __launch_bounds__(256) void k_attn_stats(const float* __restrict__ q,
        float* __restrict__ rowm, float* __restrict__ rowl) {
    __shared__ float Qt[64][65];   // [r][d]
    __shared__ float Kt[64][68];   // [d][j]
    __shared__ float mS[64], lS[64];
    const int b = blockIdx.z, hd = blockIdx.y, it = blockIdx.x;
    const int i0 = it * 64;
    const int tid = threadIdx.x, tx = tid & 15, ty = tid >> 4;
    const float* qb = q + b * (Cch * Npt);
    // gather Q tile: channel tid, points p0..p0+15 (float4 along point dim)
    { int s = tid >> 6, d = tid & 63;
      const float* src = qb + tid * Npt + hd * 512 + (i0 >> 2);
      #pragma unroll
      for (int pg = 0; pg < 4; ++pg) {
          float4 q4 = *(const float4*)(src + pg * 4);
          Qt[(pg * 4 + 0) * 4 + s][d] = q4.x;
          Qt[(pg * 4 + 1) * 4 + s][d] = q4.y;
          Qt[(pg * 4 + 2) * 4 + s][d] = q4.z;
          Qt[(pg * 4 + 3) * 4 + s][d] = q4.w;
      } }
    if (tid < 64) { mS[tid] = -1e30f; lS[tid] = 0.f; }
    const float* kbase = qb + (hd * 64) * Npt;
    for (int j0 = 0; j0 < Npt; j0 += 64) {
        __syncthreads();
        { int r = tid >> 4, jq = (tid & 15) << 2;
          #pragma unroll
          for (int dd = 0; dd < 4; ++dd) {
              int d = r + dd * 16;
              float4 k4 = *(const float4*)(kbase + d * Npt + j0 + jq);
              Kt[d][jq] = k4.x; Kt[d][jq + 1] = k4.y; Kt[d][jq + 2] = k4.z; Kt[d][jq + 3] = k4.w; } }
        __syncthreads();
        float acc[4][4] = {{0.f}};
        #pragma unroll 8
        for (int kk = 0; kk < 64; ++kk) {
            float a0 = Qt[ty * 4 + 0][kk], a1 = Qt[ty * 4 + 1][kk];
            float a2 = Qt[ty * 4 + 2][kk], a3 = Qt[ty * 4 + 3][kk];
            float b0 = Kt[kk][tx * 4 + 0], b1 = Kt[kk][tx * 4 + 1];
            float b2 = Kt[kk][tx * 4 + 2], b3 = Kt[kk][tx * 4 + 3];
            acc[0][0] += a0 * b0; acc[0][1] += a0 * b1; acc[0][2] += a0 * b2; acc[0][3] += a0 * b3;
            acc[1][0] += a1 * b0; acc[1][1] += a1 * b1; acc[1][2] += a1 * b2; acc[1][3] += a1 * b3;
            acc[2][0] += a2 * b0; acc[2][1] += a2 * b1; acc[2][2] += a2 * b2; acc[2][3] += a2 * b3;
            acc[3][0] += a3 * b0; acc[3][1] += a3 * b1; acc[3][2] += a3 * b2; acc[3][3] += a3 * b3;
        }
        #pragma unroll
        for (int i = 0; i < 4; ++i) {
            int r = ty * 4 + i;
            float rm = fmaxf(fmaxf(acc[i][0], acc[i][1]), fmaxf(acc[i][2], acc[i][3]));
            #pragma unroll
            for (int off = 1; off < 16; off <<= 1) rm = fmaxf(rm, __shfl_xor(rm, off));
            float mo = mS[r];
            float nm = fmaxf(mo, rm);
            float ps = __expf(acc[i][0] - nm) + __expf(acc[i][1] - nm)
                     + __expf(acc[i][2] - nm) + __expf(acc[i][3] - nm);
            #pragma unroll
            for (int off = 1; off < 16; off <<= 1) ps += __shfl_xor(ps, off);
            if (tx == 0) { lS[r] = lS[r] * __expf(mo - nm) + ps; mS[r] = nm; }
        }
    }
    __syncthreads();
    if (tid < 64) {
        int base = (b * Hh + hd) * Npt + i0;
        rowm[base + tid] = mS[tid];
        rowl[base + tid] = lS[tid];
    }
}

// ---------------- attention pass B: T[d,j] = sum_i V[d,i]*exp(att1[i,j]), S[j] = sum_i exp(att1[i,j]) ----------------
// grid (32 j-tiles, H, B), block 256
__global__ __launch_bounds__(256) void k_attn_av(const float* __restrict__ q,
        const float* __restrict__ v, const float* __restrict__ rowm,
        const float* __restrict__ rowl, float* __restrict__ Tb, float* __restrict__ Sb) {
    __shared__ float Kt[64][68];   // [d][j] fixed
    __shared__ float Qt[64][65];   // [r][d] per chunk
    __shared__ float Vt[64][68];   // [d][ii] per chunk
    __shared__ float At[64][68];   // a1e [ii][j]
    __shared__ float Sc[64];
    const int b = blockIdx.z, hd = blockIdx.y, jt = blockIdx.x;
    const int j0 = jt * 64;
    const int tid = threadIdx.x, tx = tid & 15, ty = tid >> 4;
    const float* qb = q + b * (Cch * Npt);
    const float* kbase = qb + (hd * 64) * Npt;
    const float* vbase = v + b * (Cch * Npt) + (hd * 64) * Npt;
    { int r = tid >> 4, jq = (tid & 15) << 2;
      #pragma unroll
      for (int dd = 0; dd < 4; ++dd) {
          int d = r + dd * 16;
          float4 k4 = *(const float4*)(kbase + d * Npt + j0 + jq);
          Kt[d][jq] = k4.x; Kt[d][jq + 1] = k4.y; Kt[d][jq + 2] = k4.z; Kt[d][jq + 3] = k4.w; } }
    if (tid < 64) Sc[tid] = 0.f;
    float Tacc[4][4] = {{0.f}};
    const float* rmB = rowm + (b * Hh + hd) * Npt;
    const float* rlB = rowl + (b * Hh + hd) * Npt;
    for (int i0 = 0; i0 < Npt; i0 += 64) {
        __syncthreads();
        { int s = tid >> 6, d = tid & 63;
          const float* src = qb + tid * Npt + hd * 512 + (i0 >> 2);
          #pragma unroll
          for (int pg = 0; pg < 4; ++pg) {
              float4 q4 = *(const float4*)(src + pg * 4);
              Qt[(pg * 4 + 0) * 4 + s][d] = q4.x;
              Qt[(pg * 4 + 1) * 4 + s][d] = q4.y;
              Qt[(pg * 4 + 2) * 4 + s][d] = q4.z;
              Qt[(pg * 4 + 3) * 4 + s][d] = q4.w;
          } }
        { int r = tid >> 4, iq = (tid & 15) << 2;
          #pragma unroll
          for (int dd = 0; dd < 4; ++dd) {
              int d = r + dd * 16;
              float4 v4 = *(const float4*)(vbase + d * Npt + i0 + iq);
              Vt[d][iq] = v4.x; Vt[d][iq + 1] = v4.y; Vt[d][iq + 2] = v4.z; Vt[d][iq + 3] = v4.w; } }
        __syncthreads();
        {
            float acc[4][4] = {{0.f}};
            #pragma unroll 8
            for (int kk = 0; kk < 64; ++kk) {
                float a0 = Qt[ty * 4 + 0][kk], a1 = Qt[ty * 4 + 1][kk];
                float a2 = Qt[ty * 4 + 2][kk], a3 = Qt[ty * 4 + 3][kk];
                float b0 = Kt[kk][tx * 4 + 0], b1 = Kt[kk][tx * 4 + 1];
                float b2 = Kt[kk][tx * 4 + 2], b3 = Kt[kk][tx * 4 + 3];
                acc[0][0] += a0 * b0; acc[0][1] += a0 * b1; acc[0][2] += a0 * b2; acc[0][3] += a0 * b3;
                acc[1][0] += a1 * b0; acc[1][1] += a1 * b1; acc[1][2] += a1 * b2; acc[1][3] += a1 * b3;
                acc[2][0] += a2 * b0; acc[2][1] += a2 * b1; acc[2][2] += a2 * b2; acc[2][3] += a2 * b3;
                acc[3][0] += a3 * b0; acc[3][1] += a3 * b1; acc[3][2] += a3 * b2; acc[3][3] += a3 * b3;
            }
            #pragma unroll
            for (int i = 0; i < 4; ++i) {
                int r = ty * 4 + i;
                float m = rmB[i0 + r];
                float linv = 1.f / rlB[i0 + r];
                #pragma unroll
                for (int j = 0; j < 4; ++j) {
                    float a1v = __expf(acc[i][j] - m) * linv;  // att1 in [0,1]
                    At[r][tx * 4 + j] = __expf(a1v);
                }
            }
        }
        __syncthreads();
        #pragma unroll 8
        for (int kk = 0; kk < 64; ++kk) {
            float a0 = Vt[ty * 4 + 0][kk], a1 = Vt[ty * 4 + 1][kk];
            float a2 = Vt[ty * 4 + 2][kk], a3 = Vt[ty * 4 + 3][kk];
            float b0 = At[kk][tx * 4 + 0], b1 = At[kk][tx * 4 + 1];
            float b2 = At[kk][tx * 4 + 2], b3 = At[kk][tx * 4 + 3];
            Tacc[0][0] += a0 * b0; Tacc[0][1] += a0 * b1; Tacc[0][2] += a0 * b2; Tacc[0][3] += a0 * b3;
            Tacc[1][0] += a1 * b0; Tacc[1][1] += a1 * b1; Tacc[1][2] += a1 * b2; Tacc[1][3] += a1 * b3;
            Tacc[2][0] += a2 * b0; Tacc[2][1] += a2 * b1; Tacc[2][2] += a2 * b2; Tacc[2][3] += a2 * b3;
            Tacc[3][0] += a3 * b0; Tacc[3][1] += a3 * b1; Tacc[3][2] += a3 * b2; Tacc[3][3] += a3 * b3;
        }
        if (tid < 64) {
            float s = 0.f;
            #pragma unroll 8
            for (int kk = 0; kk < 64; ++kk) s += At[kk][tid];
            Sc[tid] += s;
        }
    }
    #pragma unroll
    for (int di = 0; di < 4; ++di) {
        float* tp = Tb + b * (Cch * Npt) + (hd * 64 + ty * 4 + di) * Npt + j0 + tx * 4;
        tp[0] = Tacc[di][0]; tp[1] = Tacc[di][1]; tp[2] = Tacc[di][2]; tp[3] = Tacc[di][3];
    }
    if (tid < 64) Sb[(b * Hh + hd) * Npt + j0 + tid] = Sc[tid];
}

// ---------------- u = h - T/S ----------------
__global__ void k_sub(const float* __restrict__ h, const float* __restrict__ Tb,
                      const float* __restrict__ Sb, float* __restrict__ u) {
    int idx = blockIdx.x * 256 + threadIdx.x;
    int n = idx & (Npt - 1);
    int c = (idx >> 11) & (Cch - 1);
    int b = idx >> 19;
    float s = Sb[(b * Hh + (c >> 6)) * Npt + n];
    u[idx] = h[idx] - Tb[idx] / s;
}

// ---------------- BN stats: per-channel mean & inv-std over (B,N) ----------------
__global__ __launch_bounds__(256) void k_bnstats(const float* __restrict__ t,
        float* __restrict__ mean, float* __restrict__ istd) {
    const int c = blockIdx.x, tid = threadIdx.x;
    float s = 0.f, s2 = 0.f;
    for (int k = tid; k < BN_CNT; k += 256) {
        int b = k >> 11, n = k & (Npt - 1);
        float x = t[(b * Cch + c) * Npt + n];
        s += x; s2 += x * x;
    }
    #pragma unroll
    for (int off = 32; off > 0; off >>= 1) { s += __shfl_down(s, off); s2 += __shfl_down(s2, off); }
    __shared__ float ps[4], ps2[4];
    if ((tid & 63) == 0) { ps[tid >> 6] = s; ps2[tid >> 6] = s2; }
    __syncthreads();
    if (tid == 0) {
        s = ps[0] + ps[1] + ps[2] + ps[3];
        s2 = ps2[0] + ps2[1] + ps2[2] + ps2[3];
        float m = s * (1.f / BN_CNT);
        float var = s2 * (1.f / BN_CNT) - m * m;
        mean[c] = m;
        istd[c] = rsqrtf(var + EPSV);
    }
}

// ---------------- y = relu(g*(t-mean)*istd + b) [+ resid]; write h (and out slice) ----------------
__global__ void k_bn_apply(const float* __restrict__ t, const float* __restrict__ mean,
        const float* __restrict__ istd, const float* __restrict__ g, const float* __restrict__ bt,
        const float* __restrict__ resid, float* __restrict__ hout, float* __restrict__ out, int layer) {
    int idx = blockIdx.x * 256 + threadIdx.x;
    int n = idx & (Npt - 1);
    int c = (idx >> 11) & (Cch - 1);
    int b = idx >> 19;
    float y = g[c] * (t[idx] - mean[c]) * istd[c] + bt[c];
    y = fmaxf(y, 0.f);
    if (resid) y += resid[idx];
    hout[idx] = y;
    if (out) out[b * (NL * Cch * Npt) + (layer * Cch + c) * Npt + n] = y;
}

extern "C" void kernel_launch(void* const* d_in, const int* in_sizes, int n_in,
                              void* d_out, int out_size, void* d_ws, size_t ws_size,
                              hipStream_t stream) {
    (void)in_sizes; (void)n_in; (void)out_size; (void)ws_size;
    const float* x    = (const float*)d_in[0];
    const float* xyz  = (const float*)d_in[1];
    const float* c1w  = (const float*)d_in[2];
    const float* posw = (const float*)d_in[3];
    const float* posb = (const float*)d_in[4];
    const float* bn1g = (const float*)d_in[5];
    const float* bn1b = (const float*)d_in[6];
    const float* qkw  = (const float*)d_in[7];
    const float* vw   = (const float*)d_in[8];
    const float* vb   = (const float*)d_in[9];
    const float* tw   = (const float*)d_in[10];
    const float* tb   = (const float*)d_in[11];
    const float* bng  = (const float*)d_in[12];
    const float* bnb  = (const float*)d_in[13];
    float* out = (float*)d_out;

    const int NE = Bsz * Cch * Npt;   // 2,097,152 elements per [b,c,n] buffer
    float* ws   = (float*)d_ws;
    float* emb  = ws;                 // xyz embedding (persist)
    float* h    = emb + NE;           // current layer input/output
    float* hin  = h + NE;             // h + emb; later reused as u = h - x_r
    float* qb   = hin + NE;           // q (shared q/k)
    float* vbuf = qb + NE;            // v; later reused as conv/t output
    float* Tb   = vbuf + NE;          // attention numerator
    float* rowm = Tb + NE;
    float* rowl = rowm + Bsz * Hh * Npt;
    float* Sb   = rowl + Bsz * Hh * Npt;
    float* meanb = Sb + Bsz * Hh * Npt;
    float* istdb = meanb + Cch;

    dim3 blk(256);
    dim3 gemmGrid(Npt / 64, Cch / 64, Bsz);
    dim3 attGrid(Npt / 64, Hh, Bsz);
    int ew  = NE / 256;       // scalar elementwise blocks
    int ew4 = NE / 4 / 256;   // float4 elementwise blocks

    k_xyz_emb<<<ew, blk, 0, stream>>>(xyz, posw, posb, emb);

    // h0 = relu(bn1(conv1_w @ x))
    k_gemm<<<gemmGrid, blk, 0, stream>>>(c1w, x, nullptr, vbuf);
    k_bnstats<<<Cch, blk, 0, stream>>>(vbuf, meanb, istdb);
    k_bn_apply<<<ew, blk, 0, stream>>>(vbuf, meanb, istdb, bn1g, bn1b, nullptr, h, nullptr, 0);

    for (int L = 0; L < NL; ++L) {
        k_add<<<ew4, blk, 0, stream>>>(h, emb, hin);
        k_gemm<<<gemmGrid, blk, 0, stream>>>(qkw + L * Cch * Cch, hin, nullptr, qb);
        k_gemm<<<gemmGrid, blk, 0, stream>>>(vw + L * Cch * Cch, hin, vb + L * Cch, vbuf);
        k_attn_stats<<<attGrid, blk, 0, stream>>>(qb, rowm, rowl);
        k_attn_av<<<attGrid, blk, 0, stream>>>(qb, vbuf, rowm, rowl, Tb, Sb);
        k_sub<<<ew, blk, 0, stream>>>(h, Tb, Sb, hin);                       // u in hin
        k_gemm<<<gemmGrid, blk, 0, stream>>>(tw + L * Cch * Cch, hin, tb + L * Cch, vbuf);
        k_bnstats<<<Cch, blk, 0, stream>>>(vbuf, meanb, istdb);
        k_bn_apply<<<ew, blk, 0, stream>>>(vbuf, meanb, istdb, bng + L * Cch, bnb + L * Cch,
                                           h, h, out, L);
    }
}

// Round 2
// 881.539 us; speedup vs baseline: 2.5115x; 2.5115x over previous
//
#include <hip/hip_runtime.h>
#include <math.h>

#define Bsz 4
#define Cch 256
#define Npt 2048
#define Hh  4
#define NL  4
#define BN_CNT (Bsz * Npt)   // 8192
#define EPSV 1e-5f

typedef _Float16 f16x8 __attribute__((ext_vector_type(8)));
typedef _Float16 f16x4 __attribute__((ext_vector_type(4)));
typedef float    f32x4 __attribute__((ext_vector_type(4)));

// ---------------- xyz embedding ----------------
__global__ void k_xyz_emb(const float* __restrict__ xyz, const float* __restrict__ pw,
                          const float* __restrict__ pb, float* __restrict__ emb) {
    int idx = blockIdx.x * 256 + threadIdx.x;
    int n = idx & (Npt - 1);
    int c = (idx >> 11) & (Cch - 1);
    int b = idx >> 19;
    const float* xz = xyz + (b * Npt + n) * 3;
    emb[idx] = pw[c * 3 + 0] * xz[0] + pw[c * 3 + 1] * xz[1] + pw[c * 3 + 2] * xz[2] + pb[c];
}

// ---------------- cast all weights to fp16 ----------------
// layout: [c1w 65536][qkw 262144][vw 262144][tw 262144]
__global__ void k_castw(const float* __restrict__ c1w, const float* __restrict__ qkw,
                        const float* __restrict__ vw, const float* __restrict__ tw,
                        _Float16* __restrict__ o) {
    int i = blockIdx.x * 256 + threadIdx.x;
    const float* src; int off;
    if (i < 65536)            { src = c1w; off = i; }
    else if (i < 327680)      { src = qkw; off = i - 65536; }
    else if (i < 589824)      { src = vw;  off = i - 327680; }
    else                      { src = tw;  off = i - 589824; }
    o[i] = (_Float16)src[off];
}

// ---------------- fused (op) + transpose + cast: out XT[b][n][c] fp16 ----------------
// mode 0: in ; mode 1: in + aux ; mode 2: in - aux * (1/Sb[bhd][n])
__global__ __launch_bounds__(256) void k_fuse_t(const float* __restrict__ in,
        const float* __restrict__ aux, const float* __restrict__ Sb,
        _Float16* __restrict__ XT, int mode) {
    __shared__ _Float16 Tt[64][72];
    __shared__ float rsL[64];
    const int b = blockIdx.z, c0 = blockIdx.y * 64, n0 = blockIdx.x * 64;
    const int t = threadIdx.x;
    const int cl = t >> 2, ns = (t & 3) * 16;
    if (mode == 2 && t < 64) rsL[t] = 1.f / Sb[(b * Hh + (c0 >> 6)) * Npt + n0 + t];
    __syncthreads();
    const float* ip = in + ((size_t)(b * Cch + c0 + cl) * Npt) + n0 + ns;
    const float* ap = aux ? aux + ((size_t)(b * Cch + c0 + cl) * Npt) + n0 + ns : nullptr;
    #pragma unroll
    for (int g = 0; g < 4; ++g) {
        float4 v = *(const float4*)(ip + g * 4);
        if (mode == 1) {
            float4 a = *(const float4*)(ap + g * 4);
            v.x += a.x; v.y += a.y; v.z += a.z; v.w += a.w;
        } else if (mode == 2) {
            float4 a = *(const float4*)(ap + g * 4);
            v.x -= a.x * rsL[ns + g * 4 + 0]; v.y -= a.y * rsL[ns + g * 4 + 1];
            v.z -= a.z * rsL[ns + g * 4 + 2]; v.w -= a.w * rsL[ns + g * 4 + 3];
        }
        Tt[ns + g * 4 + 0][cl] = (_Float16)v.x;
        Tt[ns + g * 4 + 1][cl] = (_Float16)v.y;
        Tt[ns + g * 4 + 2][cl] = (_Float16)v.z;
        Tt[ns + g * 4 + 3][cl] = (_Float16)v.w;
    }
    __syncthreads();
    int nl = t >> 2, cs = (t & 3) * 16;
    _Float16* op = XT + ((size_t)(b * Npt + n0 + nl) * Cch) + c0 + cs;
    #pragma unroll
    for (int g = 0; g < 4; ++g)
        *(f16x4*)(op + g * 4) = *(f16x4*)&Tt[nl][cs + g * 4];
}

// ---------------- MFMA GEMM: Y[b,o,n] = sum_c W[o,c] X[b,c,n] (+bias) ----------------
// A = W fp16 [256][256]; B = XT fp16 [b][n][c]. grid (32,4,4), block 256 (4 waves).
// mode 0: Yf fp32 [b][o][n]; mode 1: Yb fp16 [b][o][n]; mode 2: write Qg + Kt (quirky gather + transpose)
__global__ __launch_bounds__(256) void k_gemm_mfma(const _Float16* __restrict__ Wb,
        const _Float16* __restrict__ XT, const float* __restrict__ bias,
        float* __restrict__ Yf, _Float16* __restrict__ Yb,
        _Float16* __restrict__ Qg, _Float16* __restrict__ Kt, int mode) {
    __shared__ float EpF[64][68];          // epilogue stage (aliased as fp16 [64][72])
    const int b = blockIdx.z, o0 = blockIdx.y * 64, n0 = blockIdx.x * 64;
    const int tid = threadIdx.x, w = tid >> 6, quad = (tid >> 4) & 3, tx = tid & 15;
    const _Float16* Arow = Wb + (o0 + w * 16 + tx) * Cch + quad * 8;
    const _Float16* Brow = XT + ((size_t)(b * Npt + n0 + tx) * Cch) + quad * 8;
    f32x4 acc[4];
    #pragma unroll
    for (int s = 0; s < 4; ++s) acc[s] = (f32x4){0.f, 0.f, 0.f, 0.f};
    for (int k0 = 0; k0 < Cch; k0 += 32) {
        f16x8 a = *(const f16x8*)(Arow + k0);
        #pragma unroll
        for (int s = 0; s < 4; ++s) {
            f16x8 bb = *(const f16x8*)(Brow + s * 16 * Cch + k0);
            acc[s] = __builtin_amdgcn_mfma_f32_16x16x32_f16(a, bb, acc[s], 0, 0, 0);
        }
    }
    if (mode == 2) {
        // C frag: row o-local = w*16+quad*4+r (consecutive d), col n = n0+s*16+tx
        #pragma unroll
        for (int s = 0; s < 4; ++s) {
            int ng = n0 + s * 16 + tx;
            int d0 = w * 16 + quad * 4;
            f16x4 pk;
            pk[0] = (_Float16)acc[s][0]; pk[1] = (_Float16)acc[s][1];
            pk[2] = (_Float16)acc[s][2]; pk[3] = (_Float16)acc[s][3];
            *(f16x4*)&Kt[(((size_t)(b * Hh + (o0 >> 6)) * Npt + ng) << 6) + d0] = pk;
            int iQ = ((ng & 511) << 2) + (o0 >> 6);
            *(f16x4*)&Qg[(((size_t)(b * Hh + (ng >> 9)) * Npt + iQ) << 6) + d0] = pk;
        }
        return;
    }
    float bv[4];
    {
        int ob = o0 + w * 16 + quad * 4;
        if (bias) { bv[0] = bias[ob]; bv[1] = bias[ob + 1]; bv[2] = bias[ob + 2]; bv[3] = bias[ob + 3]; }
        else bv[0] = bv[1] = bv[2] = bv[3] = 0.f;
    }
    if (mode == 0) {
        #pragma unroll
        for (int s = 0; s < 4; ++s) {
            int ol = w * 16 + quad * 4, nl = s * 16 + tx;
            EpF[ol + 0][nl] = acc[s][0] + bv[0];
            EpF[ol + 1][nl] = acc[s][1] + bv[1];
            EpF[ol + 2][nl] = acc[s][2] + bv[2];
            EpF[ol + 3][nl] = acc[s][3] + bv[3];
        }
        __syncthreads();
        int row = tid >> 2, seg = (tid & 3) * 16;
        float* yp = Yf + ((size_t)(b * Cch + o0 + row) * Npt) + n0 + seg;
        #pragma unroll
        for (int g = 0; g < 4; ++g)
            *(float4*)(yp + g * 4) = *(float4*)&EpF[row][seg + g * 4];
    } else {
        _Float16* EpB = (_Float16*)EpF;    // [64][72]
        #pragma unroll
        for (int s = 0; s < 4; ++s) {
            int ol = w * 16 + quad * 4, nl = s * 16 + tx;
            EpB[(ol + 0) * 72 + nl] = (_Float16)(acc[s][0] + bv[0]);
            EpB[(ol + 1) * 72 + nl] = (_Float16)(acc[s][1] + bv[1]);
            EpB[(ol + 2) * 72 + nl] = (_Float16)(acc[s][2] + bv[2]);
            EpB[(ol + 3) * 72 + nl] = (_Float16)(acc[s][3] + bv[3]);
        }
        __syncthreads();
        int row = tid >> 2, seg = (tid & 3) * 16;
        _Float16* yp = Yb + ((size_t)(b * Cch + o0 + row) * Npt) + n0 + seg;
        #pragma unroll
        for (int g = 0; g < 4; ++g)
            *(f16x4*)(yp + g * 4) = *(f16x4*)&EpB[row * 72 + seg + g * 4];
    }
}

// ---------------- attention pass A: row max + row 1/sumexp of E = Qg·Kt^T ----------------
// grid (32, Hh, Bsz), block 256 (4 waves; wave w owns rows i0+w*16 .. +15)
__global__ __launch_bounds__(256) void k_attn_A(const _Float16* __restrict__ Qg,
        const _Float16* __restrict__ Kt, float* __restrict__ rowm, float* __restrict__ rowli) {
    const int b = blockIdx.z, hd = blockIdx.y, i0 = blockIdx.x * 64;
    const int tid = threadIdx.x, w = tid >> 6, quad = (tid >> 4) & 3, tx = tid & 15;
    const int bhd = b * Hh + hd;
    const _Float16* qrow = Qg + (((size_t)(bhd * Npt + i0 + w * 16 + tx)) << 6) + quad * 8;
    f16x8 qa0 = *(const f16x8*)(qrow);
    f16x8 qa1 = *(const f16x8*)(qrow + 32);
    float m[4] = {-1e30f, -1e30f, -1e30f, -1e30f};
    float l[4] = {0.f, 0.f, 0.f, 0.f};
    const _Float16* kbase = Kt + (((size_t)(bhd * Npt)) << 6);
    for (int j0 = 0; j0 < Npt; j0 += 64) {
        f32x4 e[4];
        #pragma unroll
        for (int s = 0; s < 4; ++s) {
            const _Float16* kr = kbase + ((size_t)(j0 + s * 16 + tx) << 6) + quad * 8;
            f16x8 kb0 = *(const f16x8*)(kr);
            f16x8 kb1 = *(const f16x8*)(kr + 32);
            f32x4 z = (f32x4){0.f, 0.f, 0.f, 0.f};
            z = __builtin_amdgcn_mfma_f32_16x16x32_f16(qa0, kb0, z, 0, 0, 0);
            e[s] = __builtin_amdgcn_mfma_f32_16x16x32_f16(qa1, kb1, z, 0, 0, 0);
        }
        #pragma unroll
        for (int r = 0; r < 4; ++r) {
            float rm = fmaxf(fmaxf(e[0][r], e[1][r]), fmaxf(e[2][r], e[3][r]));
            #pragma unroll
            for (int off = 1; off < 16; off <<= 1) rm = fmaxf(rm, __shfl_xor(rm, off));
            float nm = fmaxf(m[r], rm);
            float ps = __expf(e[0][r] - nm) + __expf(e[1][r] - nm)
                     + __expf(e[2][r] - nm) + __expf(e[3][r] - nm);
            #pragma unroll
            for (int off = 1; off < 16; off <<= 1) ps += __shfl_xor(ps, off);
            l[r] = l[r] * __expf(m[r] - nm) + ps;
            m[r] = nm;
        }
    }
    if (tx == 0) {
        int base = bhd * Npt + i0 + w * 16 + quad * 4;
        #pragma unroll
        for (int r = 0; r < 4; ++r) { rowm[base + r] = m[r]; rowli[base + r] = 1.f / l[r]; }
    }
}

// ---------------- attention pass B: T[d,j] = sum_i V[d,i] a1e[i,j], S[j] = sum_i a1e[i,j] ----------------
// a1e = exp(att1), att1 = exp(E - rowm) * rowli. grid (32 j-tiles, Hh, Bsz), block 256.
__global__ __launch_bounds__(256) void k_attn_B(const _Float16* __restrict__ Qg,
        const _Float16* __restrict__ Kt, const _Float16* __restrict__ Vb,
        const float* __restrict__ rowm, const float* __restrict__ rowli,
        float* __restrict__ Tb, float* __restrict__ Sb) {
    __shared__ _Float16 AtT[64][72];      // a1e transposed [j][i], 16B-aligned rows
    __shared__ float Scp[4][64];
    const int b = blockIdx.z, hd = blockIdx.y, j0 = blockIdx.x * 64;
    const int tid = threadIdx.x, w = tid >> 6, quad = (tid >> 4) & 3, tx = tid & 15;
    const int bhd = b * Hh + hd;
    f16x8 kb0[4], kb1[4];                 // K frags for this j-tile, live whole kernel
    #pragma unroll
    for (int s = 0; s < 4; ++s) {
        const _Float16* kr = Kt + (((size_t)(bhd * Npt + j0 + s * 16 + tx)) << 6) + quad * 8;
        kb0[s] = *(const f16x8*)(kr);
        kb1[s] = *(const f16x8*)(kr + 32);
    }
    f32x4 Tacc[4];
    #pragma unroll
    for (int s = 0; s < 4; ++s) Tacc[s] = (f32x4){0.f, 0.f, 0.f, 0.f};
    float scReg[4] = {0.f, 0.f, 0.f, 0.f};
    const _Float16* vrow = Vb + (size_t)(b * Cch + hd * 64 + w * 16 + tx) * Npt;
    for (int i0 = 0; i0 < Npt; i0 += 64) {
        const _Float16* qrow = Qg + (((size_t)(bhd * Npt + i0 + w * 16 + tx)) << 6) + quad * 8;
        f16x8 qa0 = *(const f16x8*)(qrow);
        f16x8 qa1 = *(const f16x8*)(qrow + 32);
        int rbase = bhd * Npt + i0 + w * 16 + quad * 4;
        float m0 = rowm[rbase], m1 = rowm[rbase + 1], m2 = rowm[rbase + 2], m3 = rowm[rbase + 3];
        float li0 = rowli[rbase], li1 = rowli[rbase + 1], li2 = rowli[rbase + 2], li3 = rowli[rbase + 3];
        #pragma unroll
        for (int s = 0; s < 4; ++s) {
            f32x4 z = (f32x4){0.f, 0.f, 0.f, 0.f};
            z = __builtin_amdgcn_mfma_f32_16x16x32_f16(qa0, kb0[s], z, 0, 0, 0);
            z = __builtin_amdgcn_mfma_f32_16x16x32_f16(qa1, kb1[s], z, 0, 0, 0);
            float a0 = __expf(__expf(z[0] - m0) * li0);
            float a1 = __expf(__expf(z[1] - m1) * li1);
            float a2 = __expf(__expf(z[2] - m2) * li2);
            float a3 = __expf(__expf(z[3] - m3) * li3);
            float cs = a0 + a1 + a2 + a3;
            cs += __shfl_xor(cs, 16);
            cs += __shfl_xor(cs, 32);
            scReg[s] += cs;
            f16x4 pk;
            pk[0] = (_Float16)a0; pk[1] = (_Float16)a1;
            pk[2] = (_Float16)a2; pk[3] = (_Float16)a3;
            *(f16x4*)&AtT[s * 16 + tx][w * 16 + quad * 4] = pk;
        }
        __syncthreads();
        const _Float16* vp = vrow + i0 + quad * 8;
        f16x8 va0 = *(const f16x8*)(vp);
        f16x8 va1 = *(const f16x8*)(vp + 32);
        #pragma unroll
        for (int s = 0; s < 4; ++s) {
            f16x8 ab0 = *(const f16x8*)&AtT[s * 16 + tx][quad * 8];
            f16x8 ab1 = *(const f16x8*)&AtT[s * 16 + tx][32 + quad * 8];
            Tacc[s] = __builtin_amdgcn_mfma_f32_16x16x32_f16(va0, ab0, Tacc[s], 0, 0, 0);
            Tacc[s] = __builtin_amdgcn_mfma_f32_16x16x32_f16(va1, ab1, Tacc[s], 0, 0, 0);
        }
        __syncthreads();
    }
    #pragma unroll
    for (int s = 0; s < 4; ++s) {
        int d = hd * 64 + w * 16 + quad * 4;
        int jg = j0 + s * 16 + tx;
        float* tp = Tb + (size_t)(b * Cch + d) * Npt + jg;
        tp[0 * Npt] = Tacc[s][0]; tp[1 * Npt] = Tacc[s][1];
        tp[2 * Npt] = Tacc[s][2]; tp[3 * Npt] = Tacc[s][3];
    }
    if (quad == 0) {
        #pragma unroll
        for (int s = 0; s < 4; ++s) Scp[w][s * 16 + tx] = scReg[s];
    }
    __syncthreads();
    if (tid < 64) Sb[bhd * Npt + j0 + tid] = Scp[0][tid] + Scp[1][tid] + Scp[2][tid] + Scp[3][tid];
}

// ---------------- BN stats ----------------
__global__ __launch_bounds__(256) void k_bnstats(const float* __restrict__ t,
        float* __restrict__ mean, float* __restrict__ istd) {
    const int c = blockIdx.x, tid = threadIdx.x;
    float s = 0.f, s2 = 0.f;
    for (int k = tid; k < BN_CNT; k += 256) {
        int b = k >> 11, n = k & (Npt - 1);
        float x = t[(size_t)(b * Cch + c) * Npt + n];
        s += x; s2 += x * x;
    }
    #pragma unroll
    for (int off = 32; off > 0; off >>= 1) { s += __shfl_down(s, off); s2 += __shfl_down(s2, off); }
    __shared__ float ps[4], ps2[4];
    if ((tid & 63) == 0) { ps[tid >> 6] = s; ps2[tid >> 6] = s2; }
    __syncthreads();
    if (tid == 0) {
        s = ps[0] + ps[1] + ps[2] + ps[3];
        s2 = ps2[0] + ps2[1] + ps2[2] + ps2[3];
        float m = s * (1.f / BN_CNT);
        float var = s2 * (1.f / BN_CNT) - m * m;
        mean[c] = m;
        istd[c] = rsqrtf(var + EPSV);
    }
}

// ---------------- BN apply + relu + residual + output slice ----------------
__global__ void k_bn_apply(const float* __restrict__ t, const float* __restrict__ mean,
        const float* __restrict__ istd, const float* __restrict__ g, const float* __restrict__ bt,
        const float* __restrict__ resid, float* __restrict__ hout, float* __restrict__ out, int layer) {
    int idx = blockIdx.x * 256 + threadIdx.x;
    int n = idx & (Npt - 1);
    int c = (idx >> 11) & (Cch - 1);
    int b = idx >> 19;
    float y = g[c] * (t[idx] - mean[c]) * istd[c] + bt[c];
    y = fmaxf(y, 0.f);
    if (resid) y += resid[idx];
    hout[idx] = y;
    if (out) out[(size_t)b * (NL * Cch * Npt) + (size_t)(layer * Cch + c) * Npt + n] = y;
}

extern "C" void kernel_launch(void* const* d_in, const int* in_sizes, int n_in,
                              void* d_out, int out_size, void* d_ws, size_t ws_size,
                              hipStream_t stream) {
    (void)in_sizes; (void)n_in; (void)out_size; (void)ws_size;
    const float* x    = (const float*)d_in[0];
    const float* xyz  = (const float*)d_in[1];
    const float* c1w  = (const float*)d_in[2];
    const float* posw = (const float*)d_in[3];
    const float* posb = (const float*)d_in[4];
    const float* bn1g = (const float*)d_in[5];
    const float* bn1b = (const float*)d_in[6];
    const float* qkw  = (const float*)d_in[7];
    const float* vw   = (const float*)d_in[8];
    const float* vb   = (const float*)d_in[9];
    const float* tw   = (const float*)d_in[10];
    const float* tb   = (const float*)d_in[11];
    const float* bng  = (const float*)d_in[12];
    const float* bnb  = (const float*)d_in[13];
    float* out = (float*)d_out;

    const size_t NE = (size_t)Bsz * Cch * Npt;   // 2,097,152
    char* W = (char*)d_ws;
    float* emb   = (float*)W;                 W += NE * 4;
    float* h     = (float*)W;                 W += NE * 4;
    float* vbuf  = (float*)W;                 W += NE * 4;
    float* Tb    = (float*)W;                 W += NE * 4;
    _Float16* XT = (_Float16*)W;              W += NE * 2;
    _Float16* Qg = (_Float16*)W;              W += NE * 2;
    _Float16* Kt = (_Float16*)W;              W += NE * 2;
    _Float16* Vb = (_Float16*)W;              W += NE * 2;
    _Float16* wbf = (_Float16*)W;             W += 851968 * 2;
    float* rowm  = (float*)W;                 W += Bsz * Hh * Npt * 4;
    float* rowli = (float*)W;                 W += Bsz * Hh * Npt * 4;
    float* Sb    = (float*)W;                 W += Bsz * Hh * Npt * 4;
    float* meanb = (float*)W;                 W += Cch * 4;
    float* istdb = (float*)W;

    dim3 blk(256);
    dim3 g4(Npt / 64, Cch / 64, Bsz);    // 32,4,4 — gemm / fuse_t / attention grids
    int ew = (int)(NE / 256);

    k_castw<<<3328, blk, 0, stream>>>(c1w, qkw, vw, tw, wbf);
    k_xyz_emb<<<ew, blk, 0, stream>>>(xyz, posw, posb, emb);

    // h0 = relu(bn1(conv1_w @ x))
    k_fuse_t<<<g4, blk, 0, stream>>>(x, nullptr, nullptr, XT, 0);
    k_gemm_mfma<<<g4, blk, 0, stream>>>(wbf, XT, nullptr, vbuf, nullptr, nullptr, nullptr, 0);
    k_bnstats<<<Cch, blk, 0, stream>>>(vbuf, meanb, istdb);
    k_bn_apply<<<ew, blk, 0, stream>>>(vbuf, meanb, istdb, bn1g, bn1b, nullptr, h, nullptr, 0);

    for (int L = 0; L < NL; ++L) {
        const _Float16* qkL = wbf + 65536 + (size_t)L * 65536;
        const _Float16* vL  = wbf + 327680 + (size_t)L * 65536;
        const _Float16* tL  = wbf + 589824 + (size_t)L * 65536;
        k_fuse_t<<<g4, blk, 0, stream>>>(h, emb, nullptr, XT, 1);
        k_gemm_mfma<<<g4, blk, 0, stream>>>(qkL, XT, nullptr, nullptr, nullptr, Qg, Kt, 2);
        k_gemm_mfma<<<g4, blk, 0, stream>>>(vL, XT, vb + L * Cch, nullptr, Vb, nullptr, nullptr, 1);
        k_attn_A<<<g4, blk, 0, stream>>>(Qg, Kt, rowm, rowli);
        k_attn_B<<<g4, blk, 0, stream>>>(Qg, Kt, Vb, rowm, rowli, Tb, Sb);
        k_fuse_t<<<g4, blk, 0, stream>>>(h, Tb, Sb, XT, 2);
        k_gemm_mfma<<<g4, blk, 0, stream>>>(tL, XT, tb + L * Cch, vbuf, nullptr, nullptr, nullptr, 0);
        k_bnstats<<<Cch, blk, 0, stream>>>(vbuf, meanb, istdb);
        k_bn_apply<<<ew, blk, 0, stream>>>(vbuf, meanb, istdb, bng + L * Cch, bnb + L * Cch,
                                           h, h, out, L);
    }
}

// Round 3
// 850.426 us; speedup vs baseline: 2.6034x; 1.0366x over previous
//
#include <hip/hip_runtime.h>
#include <math.h>

#define Bsz 4
#define Cch 256
#define Npt 2048
#define Hh  4
#define NL  4
#define BN_CNT (Bsz * Npt)   // 8192
#define EPSV 1e-5f
#define NROW (16 * Npt)      // 32768 attention rows total (bh * Npt)

typedef _Float16 f16x8 __attribute__((ext_vector_type(8)));
typedef _Float16 f16x4 __attribute__((ext_vector_type(4)));
typedef float    f32x4 __attribute__((ext_vector_type(4)));

// ---------------- xyz embedding ----------------
__global__ void k_xyz_emb(const float* __restrict__ xyz, const float* __restrict__ pw,
                          const float* __restrict__ pb, float* __restrict__ emb) {
    int idx = blockIdx.x * 256 + threadIdx.x;
    int n = idx & (Npt - 1);
    int c = (idx >> 11) & (Cch - 1);
    int b = idx >> 19;
    const float* xz = xyz + (b * Npt + n) * 3;
    emb[idx] = pw[c * 3 + 0] * xz[0] + pw[c * 3 + 1] * xz[1] + pw[c * 3 + 2] * xz[2] + pb[c];
}

// ---------------- cast all weights to fp16 ----------------
__global__ void k_castw(const float* __restrict__ c1w, const float* __restrict__ qkw,
                        const float* __restrict__ vw, const float* __restrict__ tw,
                        _Float16* __restrict__ o) {
    int i = blockIdx.x * 256 + threadIdx.x;
    const float* src; int off;
    if (i < 65536)            { src = c1w; off = i; }
    else if (i < 327680)      { src = qkw; off = i - 65536; }
    else if (i < 589824)      { src = vw;  off = i - 327680; }
    else                      { src = tw;  off = i - 589824; }
    o[i] = (_Float16)src[off];
}

// ---------------- fused (op) + transpose + cast: out XT[b][n][c] fp16 ----------------
// mode 0: in ; mode 1: in + aux
__global__ __launch_bounds__(256) void k_fuse_t(const float* __restrict__ in,
        const float* __restrict__ aux, _Float16* __restrict__ XT, int mode) {
    __shared__ _Float16 Tt[64][72];
    const int b = blockIdx.z, c0 = blockIdx.y * 64, n0 = blockIdx.x * 64;
    const int t = threadIdx.x;
    const int cl = t >> 2, ns = (t & 3) * 16;
    const float* ip = in + ((size_t)(b * Cch + c0 + cl) * Npt) + n0 + ns;
    const float* ap = aux ? aux + ((size_t)(b * Cch + c0 + cl) * Npt) + n0 + ns : nullptr;
    #pragma unroll
    for (int g = 0; g < 4; ++g) {
        float4 v = *(const float4*)(ip + g * 4);
        if (mode == 1) {
            float4 a = *(const float4*)(ap + g * 4);
            v.x += a.x; v.y += a.y; v.z += a.z; v.w += a.w;
        }
        Tt[ns + g * 4 + 0][cl] = (_Float16)v.x;
        Tt[ns + g * 4 + 1][cl] = (_Float16)v.y;
        Tt[ns + g * 4 + 2][cl] = (_Float16)v.z;
        Tt[ns + g * 4 + 3][cl] = (_Float16)v.w;
    }
    __syncthreads();
    int nl = t >> 2, cs = (t & 3) * 16;
    _Float16* op = XT + ((size_t)(b * Npt + n0 + nl) * Cch) + c0 + cs;
    #pragma unroll
    for (int g = 0; g < 4; ++g)
        *(f16x4*)(op + g * 4) = *(f16x4*)&Tt[nl][cs + g * 4];
}

// ---------------- MFMA GEMM: Y[b,o,n] = sum_c W[o,c] X[b,c,n] (+bias) ----------------
__global__ __launch_bounds__(256) void k_gemm_mfma(const _Float16* __restrict__ Wb,
        const _Float16* __restrict__ XT, const float* __restrict__ bias,
        float* __restrict__ Yf, _Float16* __restrict__ Yb,
        _Float16* __restrict__ Qg, _Float16* __restrict__ Kt, int mode) {
    __shared__ float EpF[64][68];          // epilogue stage (aliased as fp16 [64][72])
    const int b = blockIdx.z, o0 = blockIdx.y * 64, n0 = blockIdx.x * 64;
    const int tid = threadIdx.x, w = tid >> 6, quad = (tid >> 4) & 3, tx = tid & 15;
    const _Float16* Arow = Wb + (o0 + w * 16 + tx) * Cch + quad * 8;
    const _Float16* Brow = XT + ((size_t)(b * Npt + n0 + tx) * Cch) + quad * 8;
    f32x4 acc[4];
    #pragma unroll
    for (int s = 0; s < 4; ++s) acc[s] = (f32x4){0.f, 0.f, 0.f, 0.f};
    for (int k0 = 0; k0 < Cch; k0 += 32) {
        f16x8 a = *(const f16x8*)(Arow + k0);
        #pragma unroll
        for (int s = 0; s < 4; ++s) {
            f16x8 bb = *(const f16x8*)(Brow + s * 16 * Cch + k0);
            acc[s] = __builtin_amdgcn_mfma_f32_16x16x32_f16(a, bb, acc[s], 0, 0, 0);
        }
    }
    if (mode == 2) {
        #pragma unroll
        for (int s = 0; s < 4; ++s) {
            int ng = n0 + s * 16 + tx;
            int d0 = w * 16 + quad * 4;
            f16x4 pk;
            pk[0] = (_Float16)acc[s][0]; pk[1] = (_Float16)acc[s][1];
            pk[2] = (_Float16)acc[s][2]; pk[3] = (_Float16)acc[s][3];
            *(f16x4*)&Kt[(((size_t)(b * Hh + (o0 >> 6)) * Npt + ng) << 6) + d0] = pk;
            int iQ = ((ng & 511) << 2) + (o0 >> 6);
            *(f16x4*)&Qg[(((size_t)(b * Hh + (ng >> 9)) * Npt + iQ) << 6) + d0] = pk;
        }
        return;
    }
    float bv[4];
    {
        int ob = o0 + w * 16 + quad * 4;
        if (bias) { bv[0] = bias[ob]; bv[1] = bias[ob + 1]; bv[2] = bias[ob + 2]; bv[3] = bias[ob + 3]; }
        else bv[0] = bv[1] = bv[2] = bv[3] = 0.f;
    }
    if (mode == 0) {
        #pragma unroll
        for (int s = 0; s < 4; ++s) {
            int ol = w * 16 + quad * 4, nl = s * 16 + tx;
            EpF[ol + 0][nl] = acc[s][0] + bv[0];
            EpF[ol + 1][nl] = acc[s][1] + bv[1];
            EpF[ol + 2][nl] = acc[s][2] + bv[2];
            EpF[ol + 3][nl] = acc[s][3] + bv[3];
        }
        __syncthreads();
        int row = tid >> 2, seg = (tid & 3) * 16;
        float* yp = Yf + ((size_t)(b * Cch + o0 + row) * Npt) + n0 + seg;
        #pragma unroll
        for (int g = 0; g < 4; ++g)
            *(float4*)(yp + g * 4) = *(float4*)&EpF[row][seg + g * 4];
    } else {
        _Float16* EpB = (_Float16*)EpF;    // [64][72]
        #pragma unroll
        for (int s = 0; s < 4; ++s) {
            int ol = w * 16 + quad * 4, nl = s * 16 + tx;
            EpB[(ol + 0) * 72 + nl] = (_Float16)(acc[s][0] + bv[0]);
            EpB[(ol + 1) * 72 + nl] = (_Float16)(acc[s][1] + bv[1]);
            EpB[(ol + 2) * 72 + nl] = (_Float16)(acc[s][2] + bv[2]);
            EpB[(ol + 3) * 72 + nl] = (_Float16)(acc[s][3] + bv[3]);
        }
        __syncthreads();
        int row = tid >> 2, seg = (tid & 3) * 16;
        _Float16* yp = Yb + ((size_t)(b * Cch + o0 + row) * Npt) + n0 + seg;
        #pragma unroll
        for (int g = 0; g < 4; ++g)
            *(f16x4*)(yp + g * 4) = *(f16x4*)&EpB[row * 72 + seg + g * 4];
    }
}

// ---------------- attention pass A: per-lane online (m,l) over a 512-col chunk ----------------
// grid (32 i-tiles, 4 j-chunks, 16 bh), block 256. No intra-loop shuffles.
__global__ __launch_bounds__(256) void k_attn_A(const _Float16* __restrict__ Qg,
        const _Float16* __restrict__ Kt, float* __restrict__ mP, float* __restrict__ lP) {
    const int bh = blockIdx.z, jc = blockIdx.y, i0 = blockIdx.x * 64;
    const int tid = threadIdx.x, w = tid >> 6, quad = (tid >> 4) & 3, tx = tid & 15;
    const _Float16* qrow = Qg + (((size_t)(bh * Npt + i0 + w * 16 + tx)) << 6) + quad * 8;
    f16x8 qa0 = *(const f16x8*)(qrow);
    f16x8 qa1 = *(const f16x8*)(qrow + 32);
    float m[4] = {-1e30f, -1e30f, -1e30f, -1e30f};
    float l[4] = {0.f, 0.f, 0.f, 0.f};
    const _Float16* kbase = Kt + (((size_t)(bh * Npt)) << 6);
    const int jend = jc * 512 + 512;
    for (int j0 = jc * 512; j0 < jend; j0 += 64) {
        f32x4 e[4];
        #pragma unroll
        for (int s = 0; s < 4; ++s) {
            const _Float16* kr = kbase + ((size_t)(j0 + s * 16 + tx) << 6) + quad * 8;
            f16x8 kb0 = *(const f16x8*)(kr);
            f16x8 kb1 = *(const f16x8*)(kr + 32);
            f32x4 z = (f32x4){0.f, 0.f, 0.f, 0.f};
            z = __builtin_amdgcn_mfma_f32_16x16x32_f16(qa0, kb0, z, 0, 0, 0);
            e[s] = __builtin_amdgcn_mfma_f32_16x16x32_f16(qa1, kb1, z, 0, 0, 0);
        }
        #pragma unroll
        for (int r = 0; r < 4; ++r) {
            float lm = fmaxf(fmaxf(e[0][r], e[1][r]), fmaxf(e[2][r], e[3][r]));
            float nm = fmaxf(m[r], lm);
            l[r] = l[r] * __expf(m[r] - nm)
                 + __expf(e[0][r] - nm) + __expf(e[1][r] - nm)
                 + __expf(e[2][r] - nm) + __expf(e[3][r] - nm);
            m[r] = nm;
        }
    }
    // one butterfly merge across the 16 tx lanes, per row
    #pragma unroll
    for (int r = 0; r < 4; ++r) {
        float mm = m[r], ll = l[r];
        #pragma unroll
        for (int off = 1; off < 16; off <<= 1) {
            float om = __shfl_xor(mm, off), ol = __shfl_xor(ll, off);
            float nm = fmaxf(mm, om);
            ll = ll * __expf(mm - nm) + ol * __expf(om - nm);
            mm = nm;
        }
        if (tx == 0) {
            int idx = bh * Npt + i0 + w * 16 + quad * 4 + r;
            mP[jc * NROW + idx] = mm;
            lP[jc * NROW + idx] = ll;
        }
    }
}

// ---------------- combine chunk (m,l) partials -> rowm, rowli ----------------
__global__ void k_mlcomb(const float* __restrict__ mP, const float* __restrict__ lP,
                         float* __restrict__ rowm, float* __restrict__ rowli) {
    int row = blockIdx.x * 256 + threadIdx.x;    // NROW threads
    float m0 = mP[row], m1 = mP[NROW + row], m2 = mP[2 * NROW + row], m3 = mP[3 * NROW + row];
    float m = fmaxf(fmaxf(m0, m1), fmaxf(m2, m3));
    float l = lP[row] * __expf(m0 - m) + lP[NROW + row] * __expf(m1 - m)
            + lP[2 * NROW + row] * __expf(m2 - m) + lP[3 * NROW + row] * __expf(m3 - m);
    rowm[row] = m;
    rowli[row] = 1.f / l;
}

// ---------------- attention pass B: partial T/S over a 512-row i-chunk ----------------
// grid (32 j-tiles, 4 i-chunks, 16 bh), block 256.
// Tp fp16 [ic][b][c][n]; Sp fp32 [ic][bh][n]
__global__ __launch_bounds__(256) void k_attn_B(const _Float16* __restrict__ Qg,
        const _Float16* __restrict__ Kt, const _Float16* __restrict__ Vb,
        const float* __restrict__ rowm, const float* __restrict__ rowli,
        _Float16* __restrict__ Tp, float* __restrict__ Sp) {
    __shared__ _Float16 AtT[64][72];      // a1e transposed [j][i]
    __shared__ float Scp[4][64];
    const int bh = blockIdx.z, ic = blockIdx.y, j0 = blockIdx.x * 64;
    const int b = bh >> 2, hd = bh & 3;
    const int tid = threadIdx.x, w = tid >> 6, quad = (tid >> 4) & 3, tx = tid & 15;
    f16x8 kb0[4], kb1[4];
    #pragma unroll
    for (int s = 0; s < 4; ++s) {
        const _Float16* kr = Kt + (((size_t)(bh * Npt + j0 + s * 16 + tx)) << 6) + quad * 8;
        kb0[s] = *(const f16x8*)(kr);
        kb1[s] = *(const f16x8*)(kr + 32);
    }
    f32x4 Tacc[4];
    #pragma unroll
    for (int s = 0; s < 4; ++s) Tacc[s] = (f32x4){0.f, 0.f, 0.f, 0.f};
    float scReg[4] = {0.f, 0.f, 0.f, 0.f};
    const _Float16* vrow = Vb + (size_t)(b * Cch + hd * 64 + w * 16 + tx) * Npt;
    const int iend = ic * 512 + 512;
    for (int i0 = ic * 512; i0 < iend; i0 += 64) {
        const _Float16* qrow = Qg + (((size_t)(bh * Npt + i0 + w * 16 + tx)) << 6) + quad * 8;
        f16x8 qa0 = *(const f16x8*)(qrow);
        f16x8 qa1 = *(const f16x8*)(qrow + 32);
        int rbase = bh * Npt + i0 + w * 16 + quad * 4;
        float m0 = rowm[rbase], m1 = rowm[rbase + 1], m2 = rowm[rbase + 2], m3 = rowm[rbase + 3];
        float li0 = rowli[rbase], li1 = rowli[rbase + 1], li2 = rowli[rbase + 2], li3 = rowli[rbase + 3];
        #pragma unroll
        for (int s = 0; s < 4; ++s) {
            f32x4 z = (f32x4){0.f, 0.f, 0.f, 0.f};
            z = __builtin_amdgcn_mfma_f32_16x16x32_f16(qa0, kb0[s], z, 0, 0, 0);
            z = __builtin_amdgcn_mfma_f32_16x16x32_f16(qa1, kb1[s], z, 0, 0, 0);
            float a0 = __expf(__expf(z[0] - m0) * li0);
            float a1 = __expf(__expf(z[1] - m1) * li1);
            float a2 = __expf(__expf(z[2] - m2) * li2);
            float a3 = __expf(__expf(z[3] - m3) * li3);
            float cs = a0 + a1 + a2 + a3;
            cs += __shfl_xor(cs, 16);
            cs += __shfl_xor(cs, 32);
            scReg[s] += cs;
            f16x4 pk;
            pk[0] = (_Float16)a0; pk[1] = (_Float16)a1;
            pk[2] = (_Float16)a2; pk[3] = (_Float16)a3;
            *(f16x4*)&AtT[s * 16 + tx][w * 16 + quad * 4] = pk;
        }
        __syncthreads();
        const _Float16* vp = vrow + i0 + quad * 8;
        f16x8 va0 = *(const f16x8*)(vp);
        f16x8 va1 = *(const f16x8*)(vp + 32);
        #pragma unroll
        for (int s = 0; s < 4; ++s) {
            f16x8 ab0 = *(const f16x8*)&AtT[s * 16 + tx][quad * 8];
            f16x8 ab1 = *(const f16x8*)&AtT[s * 16 + tx][32 + quad * 8];
            Tacc[s] = __builtin_amdgcn_mfma_f32_16x16x32_f16(va0, ab0, Tacc[s], 0, 0, 0);
            Tacc[s] = __builtin_amdgcn_mfma_f32_16x16x32_f16(va1, ab1, Tacc[s], 0, 0, 0);
        }
        __syncthreads();
    }
    const size_t NE = (size_t)Bsz * Cch * Npt;
    #pragma unroll
    for (int s = 0; s < 4; ++s) {
        int d = hd * 64 + w * 16 + quad * 4;
        int jg = j0 + s * 16 + tx;
        _Float16* tp = Tp + ic * NE + (size_t)(b * Cch + d) * Npt + jg;
        tp[0 * Npt] = (_Float16)Tacc[s][0]; tp[1 * Npt] = (_Float16)Tacc[s][1];
        tp[2 * Npt] = (_Float16)Tacc[s][2]; tp[3 * Npt] = (_Float16)Tacc[s][3];
    }
    if (quad == 0) {
        #pragma unroll
        for (int s = 0; s < 4; ++s) Scp[w][s * 16 + tx] = scReg[s];
    }
    __syncthreads();
    if (tid < 64)
        Sp[ic * NROW + bh * Npt + j0 + tid] = Scp[0][tid] + Scp[1][tid] + Scp[2][tid] + Scp[3][tid];
}

// ---------------- reduce T/S partials, u = h - T/S, transpose+cast -> XT ----------------
__global__ __launch_bounds__(256) void k_redT_fuse(const float* __restrict__ h,
        const _Float16* __restrict__ Tp, const float* __restrict__ Sp,
        _Float16* __restrict__ XT) {
    __shared__ _Float16 Tt[64][72];
    __shared__ float rsL[64];
    const int b = blockIdx.z, c0 = blockIdx.y * 64, n0 = blockIdx.x * 64;
    const int t = threadIdx.x;
    const int bh = b * Hh + (c0 >> 6);
    if (t < 64) {
        float s = 0.f;
        #pragma unroll
        for (int ic = 0; ic < 4; ++ic) s += Sp[ic * NROW + bh * Npt + n0 + t];
        rsL[t] = 1.f / s;
    }
    __syncthreads();
    const int cl = t >> 2, ns = (t & 3) * 16;
    const size_t NE = (size_t)Bsz * Cch * Npt;
    const size_t rowoff = ((size_t)(b * Cch + c0 + cl) * Npt) + n0 + ns;
    float tv[16];
    #pragma unroll
    for (int e = 0; e < 16; ++e) tv[e] = 0.f;
    #pragma unroll
    for (int ic = 0; ic < 4; ++ic) {
        const _Float16* q = Tp + ic * NE + rowoff;
        #pragma unroll
        for (int g = 0; g < 2; ++g) {
            f16x8 vv = *(const f16x8*)(q + g * 8);
            #pragma unroll
            for (int e = 0; e < 8; ++e) tv[g * 8 + e] += (float)vv[e];
        }
    }
    const float* hp = h + rowoff;
    #pragma unroll
    for (int g = 0; g < 4; ++g) {
        float4 hv = *(const float4*)(hp + g * 4);
        Tt[ns + g * 4 + 0][cl] = (_Float16)(hv.x - tv[g * 4 + 0] * rsL[ns + g * 4 + 0]);
        Tt[ns + g * 4 + 1][cl] = (_Float16)(hv.y - tv[g * 4 + 1] * rsL[ns + g * 4 + 1]);
        Tt[ns + g * 4 + 2][cl] = (_Float16)(hv.z - tv[g * 4 + 2] * rsL[ns + g * 4 + 2]);
        Tt[ns + g * 4 + 3][cl] = (_Float16)(hv.w - tv[g * 4 + 3] * rsL[ns + g * 4 + 3]);
    }
    __syncthreads();
    int nl = t >> 2, cs = (t & 3) * 16;
    _Float16* op = XT + ((size_t)(b * Npt + n0 + nl) * Cch) + c0 + cs;
    #pragma unroll
    for (int g = 0; g < 4; ++g)
        *(f16x4*)(op + g * 4) = *(f16x4*)&Tt[nl][cs + g * 4];
}

// ---------------- BN stats ----------------
__global__ __launch_bounds__(256) void k_bnstats(const float* __restrict__ t,
        float* __restrict__ mean, float* __restrict__ istd) {
    const int c = blockIdx.x, tid = threadIdx.x;
    float s = 0.f, s2 = 0.f;
    for (int k = tid; k < BN_CNT; k += 256) {
        int b = k >> 11, n = k & (Npt - 1);
        float x = t[(size_t)(b * Cch + c) * Npt + n];
        s += x; s2 += x * x;
    }
    #pragma unroll
    for (int off = 32; off > 0; off >>= 1) { s += __shfl_down(s, off); s2 += __shfl_down(s2, off); }
    __shared__ float ps[4], ps2[4];
    if ((tid & 63) == 0) { ps[tid >> 6] = s; ps2[tid >> 6] = s2; }
    __syncthreads();
    if (tid == 0) {
        s = ps[0] + ps[1] + ps[2] + ps[3];
        s2 = ps2[0] + ps2[1] + ps2[2] + ps2[3];
        float m = s * (1.f / BN_CNT);
        float var = s2 * (1.f / BN_CNT) - m * m;
        mean[c] = m;
        istd[c] = rsqrtf(var + EPSV);
    }
}

// ---------------- BN apply + relu + residual + output slice ----------------
__global__ void k_bn_apply(const float* __restrict__ t, const float* __restrict__ mean,
        const float* __restrict__ istd, const float* __restrict__ g, const float* __restrict__ bt,
        const float* __restrict__ resid, float* __restrict__ hout, float* __restrict__ out, int layer) {
    int idx = blockIdx.x * 256 + threadIdx.x;
    int n = idx & (Npt - 1);
    int c = (idx >> 11) & (Cch - 1);
    int b = idx >> 19;
    float y = g[c] * (t[idx] - mean[c]) * istd[c] + bt[c];
    y = fmaxf(y, 0.f);
    if (resid) y += resid[idx];
    hout[idx] = y;
    if (out) out[(size_t)b * (NL * Cch * Npt) + (size_t)(layer * Cch + c) * Npt + n] = y;
}

extern "C" void kernel_launch(void* const* d_in, const int* in_sizes, int n_in,
                              void* d_out, int out_size, void* d_ws, size_t ws_size,
                              hipStream_t stream) {
    (void)in_sizes; (void)n_in; (void)out_size; (void)ws_size;
    const float* x    = (const float*)d_in[0];
    const float* xyz  = (const float*)d_in[1];
    const float* c1w  = (const float*)d_in[2];
    const float* posw = (const float*)d_in[3];
    const float* posb = (const float*)d_in[4];
    const float* bn1g = (const float*)d_in[5];
    const float* bn1b = (const float*)d_in[6];
    const float* qkw  = (const float*)d_in[7];
    const float* vw   = (const float*)d_in[8];
    const float* vb   = (const float*)d_in[9];
    const float* tw   = (const float*)d_in[10];
    const float* tb   = (const float*)d_in[11];
    const float* bng  = (const float*)d_in[12];
    const float* bnb  = (const float*)d_in[13];
    float* out = (float*)d_out;

    const size_t NE = (size_t)Bsz * Cch * Npt;   // 2,097,152
    char* W = (char*)d_ws;
    float* emb   = (float*)W;                 W += NE * 4;
    float* h     = (float*)W;                 W += NE * 4;
    float* vbuf  = (float*)W;                 W += NE * 4;   // fp32 conv outputs
    float* TbF   = (float*)W;                 W += NE * 4;   // second half of Tp region
    (void)TbF;
    _Float16* Tp = (_Float16*)vbuf;           // fp16 [4][b][c][n] — aliases vbuf+TbF (16 MB)
    _Float16* XT = (_Float16*)W;              W += NE * 2;
    _Float16* Qg = (_Float16*)W;              W += NE * 2;
    _Float16* Kt = (_Float16*)W;              W += NE * 2;
    _Float16* Vb = (_Float16*)W;              W += NE * 2;
    _Float16* wbf = (_Float16*)W;             W += 851968 * 2;
    float* rowm  = (float*)W;                 W += NROW * 4;
    float* rowli = (float*)W;                 W += NROW * 4;
    float* mP    = (float*)W;                 W += 4 * NROW * 4;
    float* lP    = (float*)W;                 W += 4 * NROW * 4;
    float* Sp    = (float*)W;                 W += 4 * NROW * 4;
    float* meanb = (float*)W;                 W += Cch * 4;
    float* istdb = (float*)W;

    dim3 blk(256);
    dim3 g4(Npt / 64, Cch / 64, Bsz);    // 32,4,4 — gemm / fuse / reduce grids
    dim3 gA(Npt / 64, 4, 16);            // 32 tiles, 4 chunks, 16 bh — attention grids
    int ew = (int)(NE / 256);

    k_castw<<<3328, blk, 0, stream>>>(c1w, qkw, vw, tw, wbf);
    k_xyz_emb<<<ew, blk, 0, stream>>>(xyz, posw, posb, emb);

    // h0 = relu(bn1(conv1_w @ x))
    k_fuse_t<<<g4, blk, 0, stream>>>(x, nullptr, XT, 0);
    k_gemm_mfma<<<g4, blk, 0, stream>>>(wbf, XT, nullptr, vbuf, nullptr, nullptr, nullptr, 0);
    k_bnstats<<<Cch, blk, 0, stream>>>(vbuf, meanb, istdb);
    k_bn_apply<<<ew, blk, 0, stream>>>(vbuf, meanb, istdb, bn1g, bn1b, nullptr, h, nullptr, 0);

    for (int L = 0; L < NL; ++L) {
        const _Float16* qkL = wbf + 65536 + (size_t)L * 65536;
        const _Float16* vL  = wbf + 327680 + (size_t)L * 65536;
        const _Float16* tL  = wbf + 589824 + (size_t)L * 65536;
        k_fuse_t<<<g4, blk, 0, stream>>>(h, emb, XT, 1);
        k_gemm_mfma<<<g4, blk, 0, stream>>>(qkL, XT, nullptr, nullptr, nullptr, Qg, Kt, 2);
        k_gemm_mfma<<<g4, blk, 0, stream>>>(vL, XT, vb + L * Cch, nullptr, Vb, nullptr, nullptr, 1);
        k_attn_A<<<gA, blk, 0, stream>>>(Qg, Kt, mP, lP);
        k_mlcomb<<<NROW / 256, blk, 0, stream>>>(mP, lP, rowm, rowli);
        k_attn_B<<<gA, blk, 0, stream>>>(Qg, Kt, Vb, rowm, rowli, Tp, Sp);
        k_redT_fuse<<<g4, blk, 0, stream>>>(h, Tp, Sp, XT);
        k_gemm_mfma<<<g4, blk, 0, stream>>>(tL, XT, tb + L * Cch, vbuf, nullptr, nullptr, nullptr, 0);
        k_bnstats<<<Cch, blk, 0, stream>>>(vbuf, meanb, istdb);
        k_bn_apply<<<ew, blk, 0, stream>>>(vbuf, meanb, istdb, bng + L * Cch, bnb + L * Cch,
                                           h, h, out, L);
    }
}

// Round 4
// 678.693 us; speedup vs baseline: 3.2621x; 1.2530x over previous
//
#include <hip/hip_runtime.h>
#include <math.h>

#define Bsz 4
#define Cch 256
#define Npt 2048
#define Hh  4
#define NL  4
#define BN_CNT (Bsz * Npt)   // 8192
#define EPSV 1e-5f
#define NROW (16 * Npt)      // 32768 attention rows total (bh * Npt)

typedef _Float16 f16x8 __attribute__((ext_vector_type(8)));
typedef _Float16 f16x4 __attribute__((ext_vector_type(4)));
typedef float    f32x4 __attribute__((ext_vector_type(4)));

// async global->LDS, 16B per lane; LDS dst = wave-uniform base + lane*16
__device__ __forceinline__ void gld16(const _Float16* g, _Float16* l) {
    __builtin_amdgcn_global_load_lds(
        (const __attribute__((address_space(1))) unsigned int*)g,
        (__attribute__((address_space(3))) unsigned int*)l, 16, 0, 0);
}

// ---------------- xyz embedding ----------------
__global__ void k_xyz_emb(const float* __restrict__ xyz, const float* __restrict__ pw,
                          const float* __restrict__ pb, float* __restrict__ emb) {
    int idx = blockIdx.x * 256 + threadIdx.x;
    int n = idx & (Npt - 1);
    int c = (idx >> 11) & (Cch - 1);
    int b = idx >> 19;
    const float* xz = xyz + (b * Npt + n) * 3;
    emb[idx] = pw[c * 3 + 0] * xz[0] + pw[c * 3 + 1] * xz[1] + pw[c * 3 + 2] * xz[2] + pb[c];
}

// ---------------- cast all weights to fp16 ----------------
__global__ void k_castw(const float* __restrict__ c1w, const float* __restrict__ qkw,
                        const float* __restrict__ vw, const float* __restrict__ tw,
                        _Float16* __restrict__ o) {
    int i = blockIdx.x * 256 + threadIdx.x;
    const float* src; int off;
    if (i < 65536)            { src = c1w; off = i; }
    else if (i < 327680)      { src = qkw; off = i - 65536; }
    else if (i < 589824)      { src = vw;  off = i - 327680; }
    else                      { src = tw;  off = i - 589824; }
    o[i] = (_Float16)src[off];
}

// ---------------- fused (op) + transpose + cast: out XT[b][n][c] fp16 ----------------
__global__ __launch_bounds__(256) void k_fuse_t(const float* __restrict__ in,
        const float* __restrict__ aux, _Float16* __restrict__ XT, int mode) {
    __shared__ _Float16 Tt[64][72];
    const int b = blockIdx.z, c0 = blockIdx.y * 64, n0 = blockIdx.x * 64;
    const int t = threadIdx.x;
    const int cl = t >> 2, ns = (t & 3) * 16;
    const float* ip = in + ((size_t)(b * Cch + c0 + cl) * Npt) + n0 + ns;
    const float* ap = aux ? aux + ((size_t)(b * Cch + c0 + cl) * Npt) + n0 + ns : nullptr;
    #pragma unroll
    for (int g = 0; g < 4; ++g) {
        float4 v = *(const float4*)(ip + g * 4);
        if (mode == 1) {
            float4 a = *(const float4*)(ap + g * 4);
            v.x += a.x; v.y += a.y; v.z += a.z; v.w += a.w;
        }
        Tt[ns + g * 4 + 0][cl] = (_Float16)v.x;
        Tt[ns + g * 4 + 1][cl] = (_Float16)v.y;
        Tt[ns + g * 4 + 2][cl] = (_Float16)v.z;
        Tt[ns + g * 4 + 3][cl] = (_Float16)v.w;
    }
    __syncthreads();
    int nl = t >> 2, cs = (t & 3) * 16;
    _Float16* op = XT + ((size_t)(b * Npt + n0 + nl) * Cch) + c0 + cs;
    #pragma unroll
    for (int g = 0; g < 4; ++g)
        *(f16x4*)(op + g * 4) = *(f16x4*)&Tt[nl][cs + g * 4];
}

// ---------------- MFMA GEMM: Y[b,o,n] = sum_c W[o,c] X[b,c,n] (+bias) ----------------
// mode 2 writes Qg/Kt in SWIZZLED tile layout:
//   tile = 64 rows x 64 halves (8KB); chunk c (16B) of row r stored at position c^(r&7)
__global__ __launch_bounds__(256) void k_gemm_mfma(const _Float16* __restrict__ Wb,
        const _Float16* __restrict__ XT, const float* __restrict__ bias,
        float* __restrict__ Yf, _Float16* __restrict__ Yb,
        _Float16* __restrict__ Qg, _Float16* __restrict__ Kt, int mode) {
    __shared__ float EpF[64][68];          // epilogue stage (aliased as fp16 [64][72])
    const int b = blockIdx.z, o0 = blockIdx.y * 64, n0 = blockIdx.x * 64;
    const int tid = threadIdx.x, w = tid >> 6, quad = (tid >> 4) & 3, tx = tid & 15;
    const _Float16* Arow = Wb + (o0 + w * 16 + tx) * Cch + quad * 8;
    const _Float16* Brow = XT + ((size_t)(b * Npt + n0 + tx) * Cch) + quad * 8;
    f32x4 acc[4];
    #pragma unroll
    for (int s = 0; s < 4; ++s) acc[s] = (f32x4){0.f, 0.f, 0.f, 0.f};
    for (int k0 = 0; k0 < Cch; k0 += 32) {
        f16x8 a = *(const f16x8*)(Arow + k0);
        #pragma unroll
        for (int s = 0; s < 4; ++s) {
            f16x8 bb = *(const f16x8*)(Brow + s * 16 * Cch + k0);
            acc[s] = __builtin_amdgcn_mfma_f32_16x16x32_f16(a, bb, acc[s], 0, 0, 0);
        }
    }
    if (mode == 2) {
        const int cch = (w << 1) + (quad >> 1);      // 16B chunk index of d0
        const int hof = (quad & 1) * 4;              // half-offset inside chunk
        #pragma unroll
        for (int s = 0; s < 4; ++s) {
            int ng = n0 + s * 16 + tx;
            f16x4 pk;
            pk[0] = (_Float16)acc[s][0]; pk[1] = (_Float16)acc[s][1];
            pk[2] = (_Float16)acc[s][2]; pk[3] = (_Float16)acc[s][3];
            // K: head = o0>>6, row = ng
            int rK = ng & 63, jt = ng >> 6;
            size_t ka = ((size_t)((b * Hh + (o0 >> 6)) * 32 + jt) << 12)
                      + rK * 64 + ((cch ^ (rK & 7)) * 8) + hof;
            *(f16x4*)&Kt[ka] = pk;
            // Q: head = ng>>9, row = quirky gather
            int iQ = ((ng & 511) << 2) + (o0 >> 6);
            int rQ = iQ & 63, it = iQ >> 6;
            size_t qa = ((size_t)((b * Hh + (ng >> 9)) * 32 + it) << 12)
                      + rQ * 64 + ((cch ^ (rQ & 7)) * 8) + hof;
            *(f16x4*)&Qg[qa] = pk;
        }
        return;
    }
    float bv[4];
    {
        int ob = o0 + w * 16 + quad * 4;
        if (bias) { bv[0] = bias[ob]; bv[1] = bias[ob + 1]; bv[2] = bias[ob + 2]; bv[3] = bias[ob + 3]; }
        else bv[0] = bv[1] = bv[2] = bv[3] = 0.f;
    }
    if (mode == 0) {
        #pragma unroll
        for (int s = 0; s < 4; ++s) {
            int ol = w * 16 + quad * 4, nl = s * 16 + tx;
            EpF[ol + 0][nl] = acc[s][0] + bv[0];
            EpF[ol + 1][nl] = acc[s][1] + bv[1];
            EpF[ol + 2][nl] = acc[s][2] + bv[2];
            EpF[ol + 3][nl] = acc[s][3] + bv[3];
        }
        __syncthreads();
        int row = tid >> 2, seg = (tid & 3) * 16;
        float* yp = Yf + ((size_t)(b * Cch + o0 + row) * Npt) + n0 + seg;
        #pragma unroll
        for (int g = 0; g < 4; ++g)
            *(float4*)(yp + g * 4) = *(float4*)&EpF[row][seg + g * 4];
    } else {
        _Float16* EpB = (_Float16*)EpF;    // [64][72]
        #pragma unroll
        for (int s = 0; s < 4; ++s) {
            int ol = w * 16 + quad * 4, nl = s * 16 + tx;
            EpB[(ol + 0) * 72 + nl] = (_Float16)(acc[s][0] + bv[0]);
            EpB[(ol + 1) * 72 + nl] = (_Float16)(acc[s][1] + bv[1]);
            EpB[(ol + 2) * 72 + nl] = (_Float16)(acc[s][2] + bv[2]);
            EpB[(ol + 3) * 72 + nl] = (_Float16)(acc[s][3] + bv[3]);
        }
        __syncthreads();
        int row = tid >> 2, seg = (tid & 3) * 16;
        _Float16* yp = Yb + ((size_t)(b * Cch + o0 + row) * Npt) + n0 + seg;
        #pragma unroll
        for (int g = 0; g < 4; ++g)
            *(f16x4*)(yp + g * 4) = *(f16x4*)&EpB[row * 72 + seg + g * 4];
    }
}

// ---------------- attention pass A: per-lane online (m,l); K staged via global_load_lds ----------------
// grid (32 i-tiles, 4 j-chunks, 16 bh), block 256. Qg/Kt are swizzled 8KB tiles.
__global__ __launch_bounds__(256) void k_attn_A(const _Float16* __restrict__ Qg,
        const _Float16* __restrict__ Kt, float* __restrict__ mP, float* __restrict__ lP) {
    __shared__ _Float16 Ksh[2][4096];
    const int bh = blockIdx.z, jc = blockIdx.y, i0 = blockIdx.x * 64;
    const int tid = threadIdx.x, w = tid >> 6, quad = (tid >> 4) & 3, tx = tid & 15;
    const int lane = tid & 63;
    const int c0 = quad ^ (tx & 7);
    const int c1 = (quad + 4) ^ (tx & 7);
    // Q frags direct from swizzled global (block-unique rows, no redundancy)
    const _Float16* Qtile = Qg + ((size_t)(bh * 32 + (i0 >> 6)) << 12);
    const int rq = w * 16 + tx;
    f16x8 qa0 = *(const f16x8*)(Qtile + rq * 64 + c0 * 8);
    f16x8 qa1 = *(const f16x8*)(Qtile + rq * 64 + c1 * 8);
    const _Float16* Kbase = Kt + ((size_t)(bh * 32) << 12);
    const int jt0 = jc * 8;
    // stage K tile jt0 into buf 0 (linear 8KB copy; swizzle baked into global image)
    {
        const _Float16* g = Kbase + ((size_t)jt0 << 12) + (w * 2) * 512 + lane * 8;
        gld16(g,       &Ksh[0][(w * 2 + 0) * 512]);
        gld16(g + 512, &Ksh[0][(w * 2 + 1) * 512]);
    }
    __syncthreads();
    float m[4] = {-1e30f, -1e30f, -1e30f, -1e30f};
    float l[4] = {0.f, 0.f, 0.f, 0.f};
    for (int t = 0; t < 8; ++t) {
        if (t < 7) {
            const _Float16* g = Kbase + ((size_t)(jt0 + t + 1) << 12) + (w * 2) * 512 + lane * 8;
            gld16(g,       &Ksh[(t + 1) & 1][(w * 2 + 0) * 512]);
            gld16(g + 512, &Ksh[(t + 1) & 1][(w * 2 + 1) * 512]);
        }
        const _Float16* kb = Ksh[t & 1];
        f32x4 e[4];
        #pragma unroll
        for (int s = 0; s < 4; ++s) {
            const _Float16* kp = kb + (s * 16 + tx) * 64;
            f16x8 kb0 = *(const f16x8*)(kp + c0 * 8);
            f16x8 kb1 = *(const f16x8*)(kp + c1 * 8);
            f32x4 z = (f32x4){0.f, 0.f, 0.f, 0.f};
            z = __builtin_amdgcn_mfma_f32_16x16x32_f16(qa0, kb0, z, 0, 0, 0);
            e[s] = __builtin_amdgcn_mfma_f32_16x16x32_f16(qa1, kb1, z, 0, 0, 0);
        }
        #pragma unroll
        for (int r = 0; r < 4; ++r) {
            float lm = fmaxf(fmaxf(e[0][r], e[1][r]), fmaxf(e[2][r], e[3][r]));
            float nm = fmaxf(m[r], lm);
            l[r] = l[r] * __expf(m[r] - nm)
                 + __expf(e[0][r] - nm) + __expf(e[1][r] - nm)
                 + __expf(e[2][r] - nm) + __expf(e[3][r] - nm);
            m[r] = nm;
        }
        __syncthreads();
    }
    #pragma unroll
    for (int r = 0; r < 4; ++r) {
        float mm = m[r], ll = l[r];
        #pragma unroll
        for (int off = 1; off < 16; off <<= 1) {
            float om = __shfl_xor(mm, off), ol = __shfl_xor(ll, off);
            float nm = fmaxf(mm, om);
            ll = ll * __expf(mm - nm) + ol * __expf(om - nm);
            mm = nm;
        }
        if (tx == 0) {
            int idx = bh * Npt + i0 + w * 16 + quad * 4 + r;
            mP[jc * NROW + idx] = mm;
            lP[jc * NROW + idx] = ll;
        }
    }
}

// ---------------- combine chunk (m,l) partials -> rowm, rowli ----------------
__global__ void k_mlcomb(const float* __restrict__ mP, const float* __restrict__ lP,
                         float* __restrict__ rowm, float* __restrict__ rowli) {
    int row = blockIdx.x * 256 + threadIdx.x;    // NROW threads
    float m0 = mP[row], m1 = mP[NROW + row], m2 = mP[2 * NROW + row], m3 = mP[3 * NROW + row];
    float m = fmaxf(fmaxf(m0, m1), fmaxf(m2, m3));
    float l = lP[row] * __expf(m0 - m) + lP[NROW + row] * __expf(m1 - m)
            + lP[2 * NROW + row] * __expf(m2 - m) + lP[3 * NROW + row] * __expf(m3 - m);
    rowm[row] = m;
    rowli[row] = 1.f / l;
}

// ---------------- attention pass B: partial T/S over a 512-row i-chunk ----------------
// grid (32 j-tiles, 4 i-chunks, 16 bh). Qg/Kt read with swizzled-tile addressing.
__global__ __launch_bounds__(256) void k_attn_B(const _Float16* __restrict__ Qg,
        const _Float16* __restrict__ Kt, const _Float16* __restrict__ Vb,
        const float* __restrict__ rowm, const float* __restrict__ rowli,
        _Float16* __restrict__ Tp, float* __restrict__ Sp) {
    __shared__ _Float16 AtT[64][72];      // a1e transposed [j][i]
    __shared__ float Scp[4][64];
    const int bh = blockIdx.z, ic = blockIdx.y, j0 = blockIdx.x * 64;
    const int b = bh >> 2, hd = bh & 3;
    const int tid = threadIdx.x, w = tid >> 6, quad = (tid >> 4) & 3, tx = tid & 15;
    const int c0 = quad ^ (tx & 7);
    const int c1 = (quad + 4) ^ (tx & 7);
    f16x8 kb0[4], kb1[4];
    {
        const _Float16* Ktile = Kt + ((size_t)(bh * 32 + (j0 >> 6)) << 12);
        #pragma unroll
        for (int s = 0; s < 4; ++s) {
            const _Float16* kp = Ktile + (s * 16 + tx) * 64;
            kb0[s] = *(const f16x8*)(kp + c0 * 8);
            kb1[s] = *(const f16x8*)(kp + c1 * 8);
        }
    }
    f32x4 Tacc[4];
    #pragma unroll
    for (int s = 0; s < 4; ++s) Tacc[s] = (f32x4){0.f, 0.f, 0.f, 0.f};
    float scReg[4] = {0.f, 0.f, 0.f, 0.f};
    const _Float16* vrow = Vb + (size_t)(b * Cch + hd * 64 + w * 16 + tx) * Npt;
    const int iend = ic * 512 + 512;
    for (int i0 = ic * 512; i0 < iend; i0 += 64) {
        const _Float16* Qtile = Qg + ((size_t)(bh * 32 + (i0 >> 6)) << 12);
        const _Float16* qp = Qtile + (w * 16 + tx) * 64;
        f16x8 qa0 = *(const f16x8*)(qp + c0 * 8);
        f16x8 qa1 = *(const f16x8*)(qp + c1 * 8);
        int rbase = bh * Npt + i0 + w * 16 + quad * 4;
        float m0 = rowm[rbase], m1 = rowm[rbase + 1], m2 = rowm[rbase + 2], m3 = rowm[rbase + 3];
        float li0 = rowli[rbase], li1 = rowli[rbase + 1], li2 = rowli[rbase + 2], li3 = rowli[rbase + 3];
        #pragma unroll
        for (int s = 0; s < 4; ++s) {
            f32x4 z = (f32x4){0.f, 0.f, 0.f, 0.f};
            z = __builtin_amdgcn_mfma_f32_16x16x32_f16(qa0, kb0[s], z, 0, 0, 0);
            z = __builtin_amdgcn_mfma_f32_16x16x32_f16(qa1, kb1[s], z, 0, 0, 0);
            float a0 = __expf(__expf(z[0] - m0) * li0);
            float a1 = __expf(__expf(z[1] - m1) * li1);
            float a2 = __expf(__expf(z[2] - m2) * li2);
            float a3 = __expf(__expf(z[3] - m3) * li3);
            float cs = a0 + a1 + a2 + a3;
            cs += __shfl_xor(cs, 16);
            cs += __shfl_xor(cs, 32);
            scReg[s] += cs;
            f16x4 pk;
            pk[0] = (_Float16)a0; pk[1] = (_Float16)a1;
            pk[2] = (_Float16)a2; pk[3] = (_Float16)a3;
            *(f16x4*)&AtT[s * 16 + tx][w * 16 + quad * 4] = pk;
        }
        __syncthreads();
        const _Float16* vp = vrow + i0 + quad * 8;
        f16x8 va0 = *(const f16x8*)(vp);
        f16x8 va1 = *(const f16x8*)(vp + 32);
        #pragma unroll
        for (int s = 0; s < 4; ++s) {
            f16x8 ab0 = *(const f16x8*)&AtT[s * 16 + tx][quad * 8];
            f16x8 ab1 = *(const f16x8*)&AtT[s * 16 + tx][32 + quad * 8];
            Tacc[s] = __builtin_amdgcn_mfma_f32_16x16x32_f16(va0, ab0, Tacc[s], 0, 0, 0);
            Tacc[s] = __builtin_amdgcn_mfma_f32_16x16x32_f16(va1, ab1, Tacc[s], 0, 0, 0);
        }
        __syncthreads();
    }
    const size_t NE = (size_t)Bsz * Cch * Npt;
    #pragma unroll
    for (int s = 0; s < 4; ++s) {
        int d = hd * 64 + w * 16 + quad * 4;
        int jg = j0 + s * 16 + tx;
        _Float16* tp = Tp + ic * NE + (size_t)(b * Cch + d) * Npt + jg;
        tp[0 * Npt] = (_Float16)Tacc[s][0]; tp[1 * Npt] = (_Float16)Tacc[s][1];
        tp[2 * Npt] = (_Float16)Tacc[s][2]; tp[3 * Npt] = (_Float16)Tacc[s][3];
    }
    if (quad == 0) {
        #pragma unroll
        for (int s = 0; s < 4; ++s) Scp[w][s * 16 + tx] = scReg[s];
    }
    __syncthreads();
    if (tid < 64)
        Sp[ic * NROW + bh * Npt + j0 + tid] = Scp[0][tid] + Scp[1][tid] + Scp[2][tid] + Scp[3][tid];
}

// ---------------- reduce T/S partials, u = h - T/S, transpose+cast -> XT ----------------
__global__ __launch_bounds__(256) void k_redT_fuse(const float* __restrict__ h,
        const _Float16* __restrict__ Tp, const float* __restrict__ Sp,
        _Float16* __restrict__ XT) {
    __shared__ _Float16 Tt[64][72];
    __shared__ float rsL[64];
    const int b = blockIdx.z, c0 = blockIdx.y * 64, n0 = blockIdx.x * 64;
    const int t = threadIdx.x;
    const int bh = b * Hh + (c0 >> 6);
    if (t < 64) {
        float s = 0.f;
        #pragma unroll
        for (int ic = 0; ic < 4; ++ic) s += Sp[ic * NROW + bh * Npt + n0 + t];
        rsL[t] = 1.f / s;
    }
    __syncthreads();
    const int cl = t >> 2, ns = (t & 3) * 16;
    const size_t NE = (size_t)Bsz * Cch * Npt;
    const size_t rowoff = ((size_t)(b * Cch + c0 + cl) * Npt) + n0 + ns;
    float tv[16];
    #pragma unroll
    for (int e = 0; e < 16; ++e) tv[e] = 0.f;
    #pragma unroll
    for (int ic = 0; ic < 4; ++ic) {
        const _Float16* q = Tp + ic * NE + rowoff;
        #pragma unroll
        for (int g = 0; g < 2; ++g) {
            f16x8 vv = *(const f16x8*)(q + g * 8);
            #pragma unroll
            for (int e = 0; e < 8; ++e) tv[g * 8 + e] += (float)vv[e];
        }
    }
    const float* hp = h + rowoff;
    #pragma unroll
    for (int g = 0; g < 4; ++g) {
        float4 hv = *(const float4*)(hp + g * 4);
        Tt[ns + g * 4 + 0][cl] = (_Float16)(hv.x - tv[g * 4 + 0] * rsL[ns + g * 4 + 0]);
        Tt[ns + g * 4 + 1][cl] = (_Float16)(hv.y - tv[g * 4 + 1] * rsL[ns + g * 4 + 1]);
        Tt[ns + g * 4 + 2][cl] = (_Float16)(hv.z - tv[g * 4 + 2] * rsL[ns + g * 4 + 2]);
        Tt[ns + g * 4 + 3][cl] = (_Float16)(hv.w - tv[g * 4 + 3] * rsL[ns + g * 4 + 3]);
    }
    __syncthreads();
    int nl = t >> 2, cs = (t & 3) * 16;
    _Float16* op = XT + ((size_t)(b * Npt + n0 + nl) * Cch) + c0 + cs;
    #pragma unroll
    for (int g = 0; g < 4; ++g)
        *(f16x4*)(op + g * 4) = *(f16x4*)&Tt[nl][cs + g * 4];
}

// ---------------- BN stats ----------------
__global__ __launch_bounds__(256) void k_bnstats(const float* __restrict__ t,
        float* __restrict__ mean, float* __restrict__ istd) {
    const int c = blockIdx.x, tid = threadIdx.x;
    float s = 0.f, s2 = 0.f;
    for (int k = tid; k < BN_CNT; k += 256) {
        int b = k >> 11, n = k & (Npt - 1);
        float x = t[(size_t)(b * Cch + c) * Npt + n];
        s += x; s2 += x * x;
    }
    #pragma unroll
    for (int off = 32; off > 0; off >>= 1) { s += __shfl_down(s, off); s2 += __shfl_down(s2, off); }
    __shared__ float ps[4], ps2[4];
    if ((tid & 63) == 0) { ps[tid >> 6] = s; ps2[tid >> 6] = s2; }
    __syncthreads();
    if (tid == 0) {
        s = ps[0] + ps[1] + ps[2] + ps[3];
        s2 = ps2[0] + ps2[1] + ps2[2] + ps2[3];
        float m = s * (1.f / BN_CNT);
        float var = s2 * (1.f / BN_CNT) - m * m;
        mean[c] = m;
        istd[c] = rsqrtf(var + EPSV);
    }
}

// ---------------- BN apply + relu + residual + output slice ----------------
__global__ void k_bn_apply(const float* __restrict__ t, const float* __restrict__ mean,
        const float* __restrict__ istd, const float* __restrict__ g, const float* __restrict__ bt,
        const float* __restrict__ resid, float* __restrict__ hout, float* __restrict__ out, int layer) {
    int idx = blockIdx.x * 256 + threadIdx.x;
    int n = idx & (Npt - 1);
    int c = (idx >> 11) & (Cch - 1);
    int b = idx >> 19;
    float y = g[c] * (t[idx] - mean[c]) * istd[c] + bt[c];
    y = fmaxf(y, 0.f);
    if (resid) y += resid[idx];
    hout[idx] = y;
    if (out) out[(size_t)b * (NL * Cch * Npt) + (size_t)(layer * Cch + c) * Npt + n] = y;
}

extern "C" void kernel_launch(void* const* d_in, const int* in_sizes, int n_in,
                              void* d_out, int out_size, void* d_ws, size_t ws_size,
                              hipStream_t stream) {
    (void)in_sizes; (void)n_in; (void)out_size; (void)ws_size;
    const float* x    = (const float*)d_in[0];
    const float* xyz  = (const float*)d_in[1];
    const float* c1w  = (const float*)d_in[2];
    const float* posw = (const float*)d_in[3];
    const float* posb = (const float*)d_in[4];
    const float* bn1g = (const float*)d_in[5];
    const float* bn1b = (const float*)d_in[6];
    const float* qkw  = (const float*)d_in[7];
    const float* vw   = (const float*)d_in[8];
    const float* vb   = (const float*)d_in[9];
    const float* tw   = (const float*)d_in[10];
    const float* tb   = (const float*)d_in[11];
    const float* bng  = (const float*)d_in[12];
    const float* bnb  = (const float*)d_in[13];
    float* out = (float*)d_out;

    const size_t NE = (size_t)Bsz * Cch * Npt;   // 2,097,152
    char* W = (char*)d_ws;
    float* emb   = (float*)W;                 W += NE * 4;
    float* h     = (float*)W;                 W += NE * 4;
    float* vbuf  = (float*)W;                 W += NE * 4;   // fp32 conv outputs
    float* TbF   = (float*)W;                 W += NE * 4;   // second half of Tp region
    (void)TbF;
    _Float16* Tp = (_Float16*)vbuf;           // fp16 [4][b][c][n] — aliases vbuf+TbF (16 MB)
    _Float16* XT = (_Float16*)W;              W += NE * 2;
    _Float16* Qg = (_Float16*)W;              W += NE * 2;
    _Float16* Kt = (_Float16*)W;              W += NE * 2;
    _Float16* Vb = (_Float16*)W;              W += NE * 2;
    _Float16* wbf = (_Float16*)W;             W += 851968 * 2;
    float* rowm  = (float*)W;                 W += NROW * 4;
    float* rowli = (float*)W;                 W += NROW * 4;
    float* mP    = (float*)W;                 W += 4 * NROW * 4;
    float* lP    = (float*)W;                 W += 4 * NROW * 4;
    float* Sp    = (float*)W;                 W += 4 * NROW * 4;
    float* meanb = (float*)W;                 W += Cch * 4;
    float* istdb = (float*)W;

    dim3 blk(256);
    dim3 g4(Npt / 64, Cch / 64, Bsz);    // 32,4,4 — gemm / fuse / reduce grids
    dim3 gA(Npt / 64, 4, 16);            // 32 tiles, 4 chunks, 16 bh — attention grids
    int ew = (int)(NE / 256);

    k_castw<<<3328, blk, 0, stream>>>(c1w, qkw, vw, tw, wbf);
    k_xyz_emb<<<ew, blk, 0, stream>>>(xyz, posw, posb, emb);

    // h0 = relu(bn1(conv1_w @ x))
    k_fuse_t<<<g4, blk, 0, stream>>>(x, nullptr, XT, 0);
    k_gemm_mfma<<<g4, blk, 0, stream>>>(wbf, XT, nullptr, vbuf, nullptr, nullptr, nullptr, 0);
    k_bnstats<<<Cch, blk, 0, stream>>>(vbuf, meanb, istdb);
    k_bn_apply<<<ew, blk, 0, stream>>>(vbuf, meanb, istdb, bn1g, bn1b, nullptr, h, nullptr, 0);

    for (int L = 0; L < NL; ++L) {
        const _Float16* qkL = wbf + 65536 + (size_t)L * 65536;
        const _Float16* vL  = wbf + 327680 + (size_t)L * 65536;
        const _Float16* tL  = wbf + 589824 + (size_t)L * 65536;
        k_fuse_t<<<g4, blk, 0, stream>>>(h, emb, XT, 1);
        k_gemm_mfma<<<g4, blk, 0, stream>>>(qkL, XT, nullptr, nullptr, nullptr, Qg, Kt, 2);
        k_gemm_mfma<<<g4, blk, 0, stream>>>(vL, XT, vb + L * Cch, nullptr, Vb, nullptr, nullptr, 1);
        k_attn_A<<<gA, blk, 0, stream>>>(Qg, Kt, mP, lP);
        k_mlcomb<<<NROW / 256, blk, 0, stream>>>(mP, lP, rowm, rowli);
        k_attn_B<<<gA, blk, 0, stream>>>(Qg, Kt, Vb, rowm, rowli, Tp, Sp);
        k_redT_fuse<<<g4, blk, 0, stream>>>(h, Tp, Sp, XT);
        k_gemm_mfma<<<g4, blk, 0, stream>>>(tL, XT, tb + L * Cch, vbuf, nullptr, nullptr, nullptr, 0);
        k_bnstats<<<Cch, blk, 0, stream>>>(vbuf, meanb, istdb);
        k_bn_apply<<<ew, blk, 0, stream>>>(vbuf, meanb, istdb, bng + L * Cch, bnb + L * Cch,
                                           h, h, out, L);
    }
}